// Round 2
// baseline (754.118 us; speedup 1.0000x reference)
//
#include <hip/hip_runtime.h>
#include <math.h>

#define BB 32
#define TT 128
#define HH 256
#define MM 1000

__device__ inline void fma4(float4& a, const float4 b, float s) {
    a.x += b.x * s; a.y += b.y * s; a.z += b.z * s; a.w += b.w * s;
}
__device__ inline void add4(float4& a, const float4 b) {
    a.x += b.x; a.y += b.y; a.z += b.z; a.w += b.w;
}

// ---------------- ws layout (floats) ----------------
// e_cum   : 0         (4096)
// hcpre   : 4096      (32768)
// baseq   : 36864     (16384)
// basep   : 53248     (8192)
// h       : 61440     (1048576)   x@proj_w+proj_b (B,T,256)
// PWall   : 1110016   (524288)    proj1_w@projo_w  (h=256, q*512+j)
// A2      : 1634304   (8388608)   (b,q,t,j=512)
// wc8     : 10022912  (256000)
// P2o     : 10278912  (4096)      p2w@projo (8,512)
// bvec    : 10283008  (512)       (p1b+p2b)@projo + pob
// ml_i    : 10283520  (32 ints)

__global__ void k_prep(const float* __restrict__ dur, float* __restrict__ e_cum,
                       int* __restrict__ ml_i, float* __restrict__ ml_out) {
    int b = blockIdx.x;
    if (threadIdx.x == 0) {
        float run = 0.f;
        const float* d = dur + b * TT;
        float* e = e_cum + b * TT;
        for (int t = 0; t < TT; ++t) { run += d[t]; e[t] = run; }
        int ml = (int)rintf(run);
        if (ml > MM) ml = MM;
        if (ml < 0) ml = 0;
        ml_i[b] = ml;
        ml_out[b] = (float)ml;
    }
}

// h = x @ proj_w + proj_b
__global__ __launch_bounds__(256) void k_h(const float* __restrict__ x,
                                           const float* __restrict__ pw,
                                           const float* __restrict__ pb,
                                           float* __restrict__ h) {
    __shared__ float xs[16][HH];
    int blk = blockIdx.x;            // b*8 + tt
    int b = blk >> 3, tt = blk & 7;
    int t0 = tt * 16;
    int tid = threadIdx.x;
    for (int e = tid; e < 16 * HH; e += 256) {
        int r = e >> 8, i = e & 255;
        xs[r][i] = x[(b * TT + t0 + r) * HH + i];
    }
    __syncthreads();
    int jg = tid & 63, rg = tid >> 6;
    int j4 = jg * 4;
    float4 bias = *(const float4*)(pb + j4);
    float4 acc[4];
    #pragma unroll
    for (int ri = 0; ri < 4; ++ri) acc[ri] = bias;
    #pragma unroll 4
    for (int i = 0; i < HH; ++i) {
        float4 wv = *(const float4*)(pw + i * HH + j4);
        #pragma unroll
        for (int ri = 0; ri < 4; ++ri) fma4(acc[ri], wv, xs[rg * 4 + ri][i]);
    }
    #pragma unroll
    for (int ri = 0; ri < 4; ++ri)
        *(float4*)(h + (b * TT + t0 + rg * 4 + ri) * HH + j4) = acc[ri];
}

__global__ __launch_bounds__(128) void k_conv(const float* __restrict__ h,
                                              const float* __restrict__ cw,
                                              const int* __restrict__ xlen,
                                              float* __restrict__ hcpre) {
    int blk = blockIdx.x;            // b*8 + o
    int b = blk >> 3, o = blk & 7;
    int t = threadIdx.x;
    int L = xlen[b];
    float acc = 0.f;
    for (int k = 0; k < 3; ++k) {
        int tk = t + k - 1;
        if (tk < 0 || tk >= TT || tk >= L) continue;
        const float* hr = h + (b * TT + tk) * HH;
        const float* wr = cw + o * HH * 3 + k;
        float a = 0.f;
        for (int i = 0; i < HH; ++i) a += hr[i] * wr[i * 3];
        acc += a;
    }
    hcpre[(b * TT + t) * 8 + o] = acc;
}

__global__ __launch_bounds__(128) void k_bases(
    const float* __restrict__ hcpre, const float* __restrict__ cb,
    const float* __restrict__ cg, const float* __restrict__ cbeta,
    const float* __restrict__ qw1, const float* __restrict__ qb1,
    const float* __restrict__ pw1, const float* __restrict__ pb1,
    const float* __restrict__ e_cum, const float* __restrict__ dur,
    const int* __restrict__ xlen,
    float* __restrict__ baseq, float* __restrict__ basep) {
    int b = blockIdx.x;
    int t = threadIdx.x;
    int L = xlen[b];
    float v[8];
    float mu = 0.f;
    #pragma unroll
    for (int o = 0; o < 8; ++o) { v[o] = hcpre[(b * TT + t) * 8 + o] + cb[o]; mu += v[o]; }
    mu *= 0.125f;
    float var = 0.f;
    #pragma unroll
    for (int o = 0; o < 8; ++o) { float d = v[o] - mu; var += d * d; }
    var *= 0.125f;
    float rs = 1.0f / sqrtf(var + 1e-5f);
    float valid = (t < L) ? 1.f : 0.f;
    #pragma unroll
    for (int o = 0; o < 8; ++o) {
        float a = (v[o] - mu) * rs * cg[o] + cbeta[o];
        v[o] = a / (1.f + expf(-a)) * valid;
    }
    float e = e_cum[b * TT + t];
    float s_ = e - dur[b * TT + t];
    #pragma unroll
    for (int j = 0; j < 4; ++j) {
        float acc = qb1[j];
        #pragma unroll
        for (int o = 0; o < 8; ++o) acc += v[o] * qw1[o * 4 + j];
        acc += e * qw1[9 * 4 + j] - s_ * qw1[8 * 4 + j];
        baseq[(b * TT + t) * 4 + j] = acc;
    }
    #pragma unroll
    for (int j = 0; j < 2; ++j) {
        float acc = pb1[j];
        #pragma unroll
        for (int o = 0; o < 8; ++o) acc += v[o] * pw1[o * 2 + j];
        acc += e * pw1[9 * 2 + j] - s_ * pw1[8 * 2 + j];
        basep[(b * TT + t) * 2 + j] = acc;
    }
}

// per (b,m): tiny MLPs -> softmax over t -> w, wc8, mel_mask  (shuffle reductions)
__global__ __launch_bounds__(128) void k_wsoft(
    const float* __restrict__ baseq, const float* __restrict__ basep,
    const float* __restrict__ qw1, const float* __restrict__ qg,
    const float* __restrict__ qbeta, const float* __restrict__ qw2,
    const float* __restrict__ qb2,
    const float* __restrict__ pw1, const float* __restrict__ pg,
    const float* __restrict__ pbeta, const float* __restrict__ pw2,
    const float* __restrict__ pb2,
    const int* __restrict__ xlen, const int* __restrict__ ml_i,
    float* __restrict__ w_out, float* __restrict__ mm_out,
    float* __restrict__ wc8) {
    int blk = blockIdx.x;
    int b = blk / MM;
    int m = blk - b * MM;
    int t = threadIdx.x;
    int ml = ml_i[b];
    bool pad = (m >= ml);
    mm_out[(b * MM + m) * TT + t] = pad ? 1.f : 0.f;
    if (pad) {
        #pragma unroll
        for (int q = 0; q < 4; ++q) w_out[((b * 4 + q) * MM + m) * TT + t] = 0.f;
        if (t < 8) wc8[(b * MM + m) * 8 + t] = 0.f;
        return;
    }
    int L = xlen[b];
    bool xm = (t >= L);
    float mp1 = (float)(m + 1);

    __shared__ float scs[4][TT];
    __shared__ float prod[8][TT];
    __shared__ float mxs[4], sms[4];

    float sc[4];
    if (!xm) {
        float z[4];
        float4 bq = *(const float4*)(baseq + (b * TT + t) * 4);
        z[0] = bq.x; z[1] = bq.y; z[2] = bq.z; z[3] = bq.w;
        #pragma unroll
        for (int j = 0; j < 4; ++j)
            z[j] += mp1 * (qw1[8 * 4 + j] - qw1[9 * 4 + j]);
        float mu = 0.25f * (z[0] + z[1] + z[2] + z[3]);
        float var = 0.f;
        #pragma unroll
        for (int j = 0; j < 4; ++j) { float d = z[j] - mu; var += d * d; }
        var *= 0.25f;
        float rs = 1.f / sqrtf(var + 1e-5f);
        float a[4];
        #pragma unroll
        for (int j = 0; j < 4; ++j) {
            float av = (z[j] - mu) * rs * qg[j] + qbeta[j];
            a[j] = av / (1.f + expf(-av));
        }
        #pragma unroll
        for (int q = 0; q < 4; ++q) {
            float s = qb2[q];
            #pragma unroll
            for (int j = 0; j < 4; ++j) s += a[j] * qw2[j * 4 + q];
            sc[q] = s;
        }
    } else {
        #pragma unroll
        for (int q = 0; q < 4; ++q) sc[q] = -__builtin_inff();
    }
    #pragma unroll
    for (int q = 0; q < 4; ++q) scs[q][t] = sc[q];
    __syncthreads();
    {   // max: 4 groups of 32 lanes
        int g = t >> 5, l = t & 31;
        float v = fmaxf(fmaxf(scs[g][l], scs[g][l + 32]),
                        fmaxf(scs[g][l + 64], scs[g][l + 96]));
        #pragma unroll
        for (int off = 16; off > 0; off >>= 1) v = fmaxf(v, __shfl_xor(v, off, 64));
        if (l == 0) mxs[g] = v;
    }
    __syncthreads();
    float wv[4];
    #pragma unroll
    for (int q = 0; q < 4; ++q) { wv[q] = expf(sc[q] - mxs[q]); scs[q][t] = wv[q]; }
    __syncthreads();
    {   // sum: 4 groups of 32 lanes
        int g = t >> 5, l = t & 31;
        float v = scs[g][l] + scs[g][l + 32] + scs[g][l + 64] + scs[g][l + 96];
        #pragma unroll
        for (int off = 16; off > 0; off >>= 1) v += __shfl_xor(v, off, 64);
        if (l == 0) sms[g] = v;
    }
    __syncthreads();
    #pragma unroll
    for (int q = 0; q < 4; ++q) {
        wv[q] = wv[q] / sms[q];
        w_out[((b * 4 + q) * MM + m) * TT + t] = wv[q];
    }
    // c branch
    float c0 = 0.f, c1 = 0.f;
    if (!xm) {
        float z0 = basep[(b * TT + t) * 2 + 0] + mp1 * (pw1[16 + 0] - pw1[18 + 0]);
        float z1 = basep[(b * TT + t) * 2 + 1] + mp1 * (pw1[16 + 1] - pw1[18 + 1]);
        float mu = 0.5f * (z0 + z1);
        float d0 = z0 - mu, d1 = z1 - mu;
        float var = 0.5f * (d0 * d0 + d1 * d1);
        float rs = 1.f / sqrtf(var + 1e-5f);
        float a0 = d0 * rs * pg[0] + pbeta[0];
        float a1 = d1 * rs * pg[1] + pbeta[1];
        a0 = a0 / (1.f + expf(-a0));
        a1 = a1 / (1.f + expf(-a1));
        c0 = pb2[0] + a0 * pw2[0] + a1 * pw2[2];
        c1 = pb2[1] + a0 * pw2[1] + a1 * pw2[3];
    }
    #pragma unroll
    for (int q = 0; q < 4; ++q) {
        prod[q * 2 + 0][t] = wv[q] * c0;
        prod[q * 2 + 1][t] = wv[q] * c1;
    }
    __syncthreads();
    {   // wc8: 8 groups of 16 lanes
        int g8 = t >> 4, l = t & 15;
        float s = 0.f;
        #pragma unroll
        for (int i = 0; i < 8; ++i) s += prod[g8][l + 16 * i];
        #pragma unroll
        for (int off = 8; off > 0; off >>= 1) s += __shfl_xor(s, off, 64);
        if (l == 0) wc8[(b * MM + m) * 8 + g8] = s;
    }
}

// PWall[h][q*512+j] = sum_c p1w[q*256+h, c] * po[c, j]
__global__ __launch_bounds__(256) void k_pw(const float* __restrict__ p1w,
                                            const float* __restrict__ po,
                                            float* __restrict__ PWall) {
    __shared__ float S[16][HH];
    int blk = blockIdx.x;        // q*16 + ht
    int q = blk >> 4, ht = blk & 15;
    int h0 = ht * 16;
    int tid = threadIdx.x;
    for (int e = tid; e < 16 * HH; e += 256) {
        int r = e >> 8, c = e & 255;
        S[r][c] = p1w[(q * HH + h0 + r) * HH + c];
    }
    __syncthreads();
    int jg = tid & 63, rg = tid >> 6;
    int ja = jg * 4, jb = 256 + jg * 4;
    float4 acc[4][2];
    #pragma unroll
    for (int r = 0; r < 4; ++r) { acc[r][0] = make_float4(0,0,0,0); acc[r][1] = make_float4(0,0,0,0); }
    #pragma unroll 2
    for (int ko = 0; ko < HH / 4; ++ko) {
        float4 lv[4];
        #pragma unroll
        for (int r = 0; r < 4; ++r) lv[r] = ((const float4*)S[rg * 4 + r])[ko];
        #pragma unroll
        for (int kk = 0; kk < 4; ++kk) {
            int c = ko * 4 + kk;
            float4 b0 = *(const float4*)(po + c * 512 + ja);
            float4 b1 = *(const float4*)(po + c * 512 + jb);
            #pragma unroll
            for (int r = 0; r < 4; ++r) {
                float s = ((const float*)&lv[r])[kk];
                fma4(acc[r][0], b0, s); fma4(acc[r][1], b1, s);
            }
        }
    }
    #pragma unroll
    for (int r = 0; r < 4; ++r) {
        int h = h0 + rg * 4 + r;
        *(float4*)(PWall + h * 2048 + q * 512 + ja) = acc[r][0];
        *(float4*)(PWall + h * 2048 + q * 512 + jb) = acc[r][1];
    }
}

// P2o = p2w@po (8,512); bvec = (p1b+p2b)@po + pob
__global__ __launch_bounds__(512) void k_small(const float* __restrict__ p2w,
    const float* __restrict__ po, const float* __restrict__ p1b,
    const float* __restrict__ p2b, const float* __restrict__ pob,
    float* __restrict__ P2o, float* __restrict__ bvec) {
    int j = threadIdx.x;
    float acc[9];
    #pragma unroll
    for (int r = 0; r < 9; ++r) acc[r] = 0.f;
    for (int c = 0; c < HH; ++c) {
        float pv = po[c * 512 + j];
        #pragma unroll
        for (int r = 0; r < 8; ++r) acc[r] += p2w[r * HH + c] * pv;
        acc[8] += (p1b[c] + p2b[c]) * pv;
    }
    #pragma unroll
    for (int r = 0; r < 8; ++r) P2o[r * 512 + j] = acc[r];
    bvec[j] = acc[8] + pob[j];
}

// A2[(b,q,t), j] = sum_c x[b,t,c] * PWall[c][q*512+j]
__global__ __launch_bounds__(256) void k_A2(const float* __restrict__ x,
                                            const float* __restrict__ PWall,
                                            float* __restrict__ A2) {
    __shared__ float S[16][HH];
    int blk = blockIdx.x;        // bt_tile*4 + q
    int q = blk & 3;
    int bt0 = (blk >> 2) * 16;
    int tid = threadIdx.x;
    for (int e = tid; e < 16 * HH; e += 256) {
        int r = e >> 8, c = e & 255;
        S[r][c] = x[(bt0 + r) * HH + c];
    }
    __syncthreads();
    int jg = tid & 63, rg = tid >> 6;
    int ja = jg * 4, jb = 256 + jg * 4;
    float4 acc[4][2];
    #pragma unroll
    for (int r = 0; r < 4; ++r) { acc[r][0] = make_float4(0,0,0,0); acc[r][1] = make_float4(0,0,0,0); }
    #pragma unroll 2
    for (int ko = 0; ko < HH / 4; ++ko) {
        float4 lv[4];
        #pragma unroll
        for (int r = 0; r < 4; ++r) lv[r] = ((const float4*)S[rg * 4 + r])[ko];
        #pragma unroll
        for (int kk = 0; kk < 4; ++kk) {
            int c = ko * 4 + kk;
            float4 b0 = *(const float4*)(PWall + c * 2048 + q * 512 + ja);
            float4 b1 = *(const float4*)(PWall + c * 2048 + q * 512 + jb);
            #pragma unroll
            for (int r = 0; r < 4; ++r) {
                float s = ((const float*)&lv[r])[kk];
                fma4(acc[r][0], b0, s); fma4(acc[r][1], b1, s);
            }
        }
    }
    #pragma unroll
    for (int r = 0; r < 4; ++r) {
        int bt = bt0 + rg * 4 + r;
        int b = bt >> 7, t = bt & 127;
        float* dst = A2 + (size_t)((b * 4 + q) * TT + t) * 512;
        *(float4*)(dst + ja) = acc[r][0];
        *(float4*)(dst + jb) = acc[r][1];
    }
}

// o[b,m,:] = W[b,m,:]@A2[b] + wc8[b,m,:]@P2o + bvec   (valid m), else pob
__global__ __launch_bounds__(256) void k_main(const float* __restrict__ w_out,
    const float* __restrict__ A2, const float* __restrict__ wc8,
    const float* __restrict__ P2o, const float* __restrict__ bvec,
    const float* __restrict__ pob, const int* __restrict__ ml_i,
    float* __restrict__ o_out) {
    __shared__ float Wl[16][512];
    int blk = blockIdx.x;            // b*63 + mt
    int b = blk / 63;
    int mt = blk - b * 63;
    int m0 = mt * 16;
    int tid = threadIdx.x;
    for (int e = tid; e < 16 * 128; e += 256) {
        int mi = e >> 7, kf = e & 127;
        int q = kf >> 5, t4 = kf & 31;
        int m = m0 + mi;
        float4 v = make_float4(0, 0, 0, 0);
        if (m < MM) v = *(const float4*)(w_out + (size_t)((b * 4 + q) * MM + m) * TT + t4 * 4);
        *(float4*)(&Wl[mi][kf * 4]) = v;
    }
    __syncthreads();
    int jg = tid & 63, rg = tid >> 6;
    int ja = jg * 4, jb = 256 + jg * 4;
    float4 acc[4][2];
    #pragma unroll
    for (int r = 0; r < 4; ++r) { acc[r][0] = make_float4(0,0,0,0); acc[r][1] = make_float4(0,0,0,0); }
    const float* Ab = A2 + (size_t)b * 512 * 512;
    #pragma unroll 2
    for (int ko = 0; ko < 128; ++ko) {
        float4 lv[4];
        #pragma unroll
        for (int r = 0; r < 4; ++r) lv[r] = ((const float4*)Wl[rg * 4 + r])[ko];
        #pragma unroll
        for (int kk = 0; kk < 4; ++kk) {
            const float* br = Ab + (size_t)(ko * 4 + kk) * 512;
            float4 b0 = *(const float4*)(br + ja);
            float4 b1 = *(const float4*)(br + jb);
            #pragma unroll
            for (int r = 0; r < 4; ++r) {
                float s = ((const float*)&lv[r])[kk];
                fma4(acc[r][0], b0, s); fma4(acc[r][1], b1, s);
            }
        }
    }
    int ml = ml_i[b];
    float4 bva = *(const float4*)(bvec + ja);
    float4 bvb = *(const float4*)(bvec + jb);
    float4 poa = *(const float4*)(pob + ja);
    float4 pobv = *(const float4*)(pob + jb);
    #pragma unroll
    for (int r = 0; r < 4; ++r) {
        int m = m0 + rg * 4 + r;
        if (m >= MM) continue;
        float* dst = o_out + (size_t)(b * MM + m) * 512;
        float4 o0, o1;
        if (m < ml) {
            o0 = acc[r][0]; o1 = acc[r][1];
            add4(o0, bva); add4(o1, bvb);
            const float* c8 = wc8 + (size_t)(b * MM + m) * 8;
            #pragma unroll
            for (int r8 = 0; r8 < 8; ++r8) {
                float cv = c8[r8];
                fma4(o0, *(const float4*)(P2o + r8 * 512 + ja), cv);
                fma4(o1, *(const float4*)(P2o + r8 * 512 + jb), cv);
            }
        } else {
            o0 = poa; o1 = pobv;
        }
        *(float4*)(dst + ja) = o0;
        *(float4*)(dst + jb) = o1;
    }
}

extern "C" void kernel_launch(void* const* d_in, const int* in_sizes, int n_in,
                              void* d_out, int out_size, void* d_ws, size_t ws_size,
                              hipStream_t stream) {
    (void)in_sizes; (void)n_in; (void)out_size; (void)ws_size;
    const float* x      = (const float*)d_in[0];
    const float* dur    = (const float*)d_in[2];
    const int*   xlen   = (const int*)d_in[3];
    const float* proj_w = (const float*)d_in[4];
    const float* proj_b = (const float*)d_in[5];
    const float* conv_w = (const float*)d_in[6];
    const float* conv_b = (const float*)d_in[7];
    const float* conv_g = (const float*)d_in[8];
    const float* conv_be= (const float*)d_in[9];
    const float* q_w1   = (const float*)d_in[10];
    const float* q_b1   = (const float*)d_in[11];
    const float* q_g    = (const float*)d_in[12];
    const float* q_be   = (const float*)d_in[13];
    const float* q_w2   = (const float*)d_in[14];
    const float* q_b2   = (const float*)d_in[15];
    const float* p_w1   = (const float*)d_in[16];
    const float* p_b1   = (const float*)d_in[17];
    const float* p_g    = (const float*)d_in[18];
    const float* p_be   = (const float*)d_in[19];
    const float* p_w2   = (const float*)d_in[20];
    const float* p_b2   = (const float*)d_in[21];
    const float* p1w    = (const float*)d_in[22];
    const float* p1b    = (const float*)d_in[23];
    const float* p2w    = (const float*)d_in[24];
    const float* p2b    = (const float*)d_in[25];
    const float* pow_   = (const float*)d_in[26];
    const float* pob    = (const float*)d_in[27];

    float* ws    = (float*)d_ws;
    float* e_cum = ws + 0;
    float* hcpre = ws + 4096;
    float* baseq = ws + 36864;
    float* basep = ws + 53248;
    float* h     = ws + 61440;
    float* PWall = ws + 1110016;
    float* A2    = ws + 1634304;
    float* wc8   = ws + 10022912;
    float* P2o   = ws + 10278912;
    float* bvec  = ws + 10283008;
    int*   ml_i  = (int*)(ws + 10283520);

    float* o_out  = (float*)d_out;                  // (B,M,512)
    float* mm_out = o_out + 16384000;               // (B,M,T)
    float* ml_out = o_out + 20480000;               // (B,)
    float* w_out  = o_out + 20480032;               // (B,Q,M,T)

    k_prep<<<dim3(BB), dim3(64), 0, stream>>>(dur, e_cum, ml_i, ml_out);
    k_h<<<dim3(BB * 8), dim3(256), 0, stream>>>(x, proj_w, proj_b, h);
    k_conv<<<dim3(BB * 8), dim3(128), 0, stream>>>(h, conv_w, xlen, hcpre);
    k_bases<<<dim3(BB), dim3(128), 0, stream>>>(hcpre, conv_b, conv_g, conv_be,
                                                q_w1, q_b1, p_w1, p_b1,
                                                e_cum, dur, xlen, baseq, basep);
    k_pw<<<dim3(64), dim3(256), 0, stream>>>(p1w, pow_, PWall);
    k_small<<<dim3(1), dim3(512), 0, stream>>>(p2w, pow_, p1b, p2b, pob, P2o, bvec);
    k_A2<<<dim3(BB * TT / 16 * 4), dim3(256), 0, stream>>>(x, PWall, A2);
    k_wsoft<<<dim3(BB * MM), dim3(128), 0, stream>>>(baseq, basep,
                                                     q_w1, q_g, q_be, q_w2, q_b2,
                                                     p_w1, p_g, p_be, p_w2, p_b2,
                                                     xlen, ml_i, w_out, mm_out, wc8);
    k_main<<<dim3(BB * 63), dim3(256), 0, stream>>>(w_out, A2, wc8, P2o, bvec,
                                                    pob, ml_i, o_out);
}

// Round 4
// 589.590 us; speedup vs baseline: 1.2791x; 1.2791x over previous
//
#include <hip/hip_runtime.h>
#include <math.h>

#define BB 32
#define TT 128
#define HH 256
#define MM 1000

typedef __attribute__((ext_vector_type(8))) short short8;
typedef __attribute__((ext_vector_type(4))) float floatx4;

__device__ inline void fma4(float4& a, const float4 b, float s) {
    a.x += b.x * s; a.y += b.y * s; a.z += b.z * s; a.w += b.w * s;
}

__device__ inline unsigned short f2bf(float f) {
    union { float f; unsigned int u; } c; c.f = f;
    unsigned int u = c.u;
    return (unsigned short)((u + 0x7FFFu + ((u >> 16) & 1u)) >> 16);
}

// ---------------- ws layout (floats) ---- (identical to R2, which passed) ----
// e_cum 0 (4096) | hcpre 4096 (32768) | baseq 36864 (16384) | basep 53248 (8192)
// h 61440 (1048576) | PWall 1110016 (524288)
// A2 1634304 (8388608)  f32 [b][k=q*128+t][j=512]
// wc8 10022912 (256000) | P2o 10278912 (4096) | bvec 10283008 (512) | ml_i 10283520

__global__ void k_prep(const float* __restrict__ dur, float* __restrict__ e_cum,
                       int* __restrict__ ml_i, float* __restrict__ ml_out) {
    int b = blockIdx.x;
    if (threadIdx.x == 0) {
        float run = 0.f;
        const float* d = dur + b * TT;
        float* e = e_cum + b * TT;
        for (int t = 0; t < TT; ++t) { run += d[t]; e[t] = run; }
        int ml = (int)rintf(run);
        if (ml > MM) ml = MM;
        if (ml < 0) ml = 0;
        ml_i[b] = ml;
        ml_out[b] = (float)ml;
    }
}

// h = x @ proj_w + proj_b
__global__ __launch_bounds__(256) void k_h(const float* __restrict__ x,
                                           const float* __restrict__ pw,
                                           const float* __restrict__ pb,
                                           float* __restrict__ h) {
    __shared__ float xs[16][HH];
    int blk = blockIdx.x;            // b*8 + tt
    int b = blk >> 3, tt = blk & 7;
    int t0 = tt * 16;
    int tid = threadIdx.x;
    for (int e = tid; e < 16 * HH; e += 256) {
        int r = e >> 8, i = e & 255;
        xs[r][i] = x[(b * TT + t0 + r) * HH + i];
    }
    __syncthreads();
    int jg = tid & 63, rg = tid >> 6;
    int j4 = jg * 4;
    float4 bias = *(const float4*)(pb + j4);
    float4 acc[4];
    #pragma unroll
    for (int ri = 0; ri < 4; ++ri) acc[ri] = bias;
    #pragma unroll 4
    for (int i = 0; i < HH; ++i) {
        float4 wv = *(const float4*)(pw + i * HH + j4);
        #pragma unroll
        for (int ri = 0; ri < 4; ++ri) fma4(acc[ri], wv, xs[rg * 4 + ri][i]);
    }
    #pragma unroll
    for (int ri = 0; ri < 4; ++ri)
        *(float4*)(h + (b * TT + t0 + rg * 4 + ri) * HH + j4) = acc[ri];
}

// conv 'SAME' K=3 over time (R2-proven version)
__global__ __launch_bounds__(128) void k_conv(const float* __restrict__ h,
                                              const float* __restrict__ cw,
                                              const int* __restrict__ xlen,
                                              float* __restrict__ hcpre) {
    int blk = blockIdx.x;            // b*8 + o
    int b = blk >> 3, o = blk & 7;
    int t = threadIdx.x;
    int L = xlen[b];
    float acc = 0.f;
    for (int k = 0; k < 3; ++k) {
        int tk = t + k - 1;
        if (tk < 0 || tk >= TT || tk >= L) continue;
        const float* hr = h + (b * TT + tk) * HH;
        const float* wr = cw + o * HH * 3 + k;
        float a = 0.f;
        for (int i = 0; i < HH; ++i) a += hr[i] * wr[i * 3];
        acc += a;
    }
    hcpre[(b * TT + t) * 8 + o] = acc;
}

__global__ __launch_bounds__(128) void k_bases(
    const float* __restrict__ hcpre, const float* __restrict__ cb,
    const float* __restrict__ cg, const float* __restrict__ cbeta,
    const float* __restrict__ qw1, const float* __restrict__ qb1,
    const float* __restrict__ pw1, const float* __restrict__ pb1,
    const float* __restrict__ e_cum, const float* __restrict__ dur,
    const int* __restrict__ xlen,
    float* __restrict__ baseq, float* __restrict__ basep) {
    int b = blockIdx.x;
    int t = threadIdx.x;
    int L = xlen[b];
    float v[8];
    float mu = 0.f;
    #pragma unroll
    for (int o = 0; o < 8; ++o) { v[o] = hcpre[(b * TT + t) * 8 + o] + cb[o]; mu += v[o]; }
    mu *= 0.125f;
    float var = 0.f;
    #pragma unroll
    for (int o = 0; o < 8; ++o) { float d = v[o] - mu; var += d * d; }
    var *= 0.125f;
    float rs = 1.0f / sqrtf(var + 1e-5f);
    float valid = (t < L) ? 1.f : 0.f;
    #pragma unroll
    for (int o = 0; o < 8; ++o) {
        float a = (v[o] - mu) * rs * cg[o] + cbeta[o];
        v[o] = a / (1.f + expf(-a)) * valid;
    }
    float e = e_cum[b * TT + t];
    float s_ = e - dur[b * TT + t];
    #pragma unroll
    for (int j = 0; j < 4; ++j) {
        float acc = qb1[j];
        #pragma unroll
        for (int o = 0; o < 8; ++o) acc += v[o] * qw1[o * 4 + j];
        acc += e * qw1[9 * 4 + j] - s_ * qw1[8 * 4 + j];
        baseq[(b * TT + t) * 4 + j] = acc;
    }
    #pragma unroll
    for (int j = 0; j < 2; ++j) {
        float acc = pb1[j];
        #pragma unroll
        for (int o = 0; o < 8; ++o) acc += v[o] * pw1[o * 2 + j];
        acc += e * pw1[9 * 2 + j] - s_ * pw1[8 * 2 + j];
        basep[(b * TT + t) * 2 + j] = acc;
    }
}

// per (b,m): tiny MLPs -> softmax over t -> w, wc8, mel_mask (R2-proven version)
__global__ __launch_bounds__(128) void k_wsoft(
    const float* __restrict__ baseq, const float* __restrict__ basep,
    const float* __restrict__ qw1, const float* __restrict__ qg,
    const float* __restrict__ qbeta, const float* __restrict__ qw2,
    const float* __restrict__ qb2,
    const float* __restrict__ pw1, const float* __restrict__ pg,
    const float* __restrict__ pbeta, const float* __restrict__ pw2,
    const float* __restrict__ pb2,
    const int* __restrict__ xlen, const int* __restrict__ ml_i,
    float* __restrict__ w_out, float* __restrict__ mm_out,
    float* __restrict__ wc8) {
    int blk = blockIdx.x;
    int b = blk / MM;
    int m = blk - b * MM;
    int t = threadIdx.x;
    int ml = ml_i[b];
    bool pad = (m >= ml);
    mm_out[(b * MM + m) * TT + t] = pad ? 1.f : 0.f;
    if (pad) {
        #pragma unroll
        for (int q = 0; q < 4; ++q) w_out[((b * 4 + q) * MM + m) * TT + t] = 0.f;
        if (t < 8) wc8[(b * MM + m) * 8 + t] = 0.f;
        return;
    }
    int L = xlen[b];
    bool xm = (t >= L);
    float mp1 = (float)(m + 1);

    __shared__ float scs[4][TT];
    __shared__ float prod[8][TT];
    __shared__ float mxs[4], sms[4];

    float sc[4];
    if (!xm) {
        float z[4];
        float4 bq = *(const float4*)(baseq + (b * TT + t) * 4);
        z[0] = bq.x; z[1] = bq.y; z[2] = bq.z; z[3] = bq.w;
        #pragma unroll
        for (int j = 0; j < 4; ++j)
            z[j] += mp1 * (qw1[8 * 4 + j] - qw1[9 * 4 + j]);
        float mu = 0.25f * (z[0] + z[1] + z[2] + z[3]);
        float var = 0.f;
        #pragma unroll
        for (int j = 0; j < 4; ++j) { float d = z[j] - mu; var += d * d; }
        var *= 0.25f;
        float rs = 1.f / sqrtf(var + 1e-5f);
        float a[4];
        #pragma unroll
        for (int j = 0; j < 4; ++j) {
            float av = (z[j] - mu) * rs * qg[j] + qbeta[j];
            a[j] = av / (1.f + expf(-av));
        }
        #pragma unroll
        for (int q = 0; q < 4; ++q) {
            float s = qb2[q];
            #pragma unroll
            for (int j = 0; j < 4; ++j) s += a[j] * qw2[j * 4 + q];
            sc[q] = s;
        }
    } else {
        #pragma unroll
        for (int q = 0; q < 4; ++q) sc[q] = -__builtin_inff();
    }
    #pragma unroll
    for (int q = 0; q < 4; ++q) scs[q][t] = sc[q];
    __syncthreads();
    {
        int g = t >> 5, l = t & 31;
        float v = fmaxf(fmaxf(scs[g][l], scs[g][l + 32]),
                        fmaxf(scs[g][l + 64], scs[g][l + 96]));
        #pragma unroll
        for (int off = 16; off > 0; off >>= 1) v = fmaxf(v, __shfl_xor(v, off, 64));
        if (l == 0) mxs[g] = v;
    }
    __syncthreads();
    float wv[4];
    #pragma unroll
    for (int q = 0; q < 4; ++q) { wv[q] = expf(sc[q] - mxs[q]); scs[q][t] = wv[q]; }
    __syncthreads();
    {
        int g = t >> 5, l = t & 31;
        float v = scs[g][l] + scs[g][l + 32] + scs[g][l + 64] + scs[g][l + 96];
        #pragma unroll
        for (int off = 16; off > 0; off >>= 1) v += __shfl_xor(v, off, 64);
        if (l == 0) sms[g] = v;
    }
    __syncthreads();
    #pragma unroll
    for (int q = 0; q < 4; ++q) {
        wv[q] = wv[q] / sms[q];
        w_out[((b * 4 + q) * MM + m) * TT + t] = wv[q];
    }
    float c0 = 0.f, c1 = 0.f;
    if (!xm) {
        float z0 = basep[(b * TT + t) * 2 + 0] + mp1 * (pw1[16 + 0] - pw1[18 + 0]);
        float z1 = basep[(b * TT + t) * 2 + 1] + mp1 * (pw1[16 + 1] - pw1[18 + 1]);
        float mu = 0.5f * (z0 + z1);
        float d0 = z0 - mu, d1 = z1 - mu;
        float var = 0.5f * (d0 * d0 + d1 * d1);
        float rs = 1.f / sqrtf(var + 1e-5f);
        float a0 = d0 * rs * pg[0] + pbeta[0];
        float a1 = d1 * rs * pg[1] + pbeta[1];
        a0 = a0 / (1.f + expf(-a0));
        a1 = a1 / (1.f + expf(-a1));
        c0 = pb2[0] + a0 * pw2[0] + a1 * pw2[2];
        c1 = pb2[1] + a0 * pw2[1] + a1 * pw2[3];
    }
    #pragma unroll
    for (int q = 0; q < 4; ++q) {
        prod[q * 2 + 0][t] = wv[q] * c0;
        prod[q * 2 + 1][t] = wv[q] * c1;
    }
    __syncthreads();
    {
        int g8 = t >> 4, l = t & 15;
        float s = 0.f;
        #pragma unroll
        for (int i = 0; i < 8; ++i) s += prod[g8][l + 16 * i];
        #pragma unroll
        for (int off = 8; off > 0; off >>= 1) s += __shfl_xor(s, off, 64);
        if (l == 0) wc8[(b * MM + m) * 8 + g8] = s;
    }
}

// PWall[h][q*512+j] = sum_c p1w[q*256+h, c] * po[c, j]
__global__ __launch_bounds__(256) void k_pw(const float* __restrict__ p1w,
                                            const float* __restrict__ po,
                                            float* __restrict__ PWall) {
    __shared__ float S[16][HH];
    int blk = blockIdx.x;        // q*16 + ht
    int q = blk >> 4, ht = blk & 15;
    int h0 = ht * 16;
    int tid = threadIdx.x;
    for (int e = tid; e < 16 * HH; e += 256) {
        int r = e >> 8, c = e & 255;
        S[r][c] = p1w[(q * HH + h0 + r) * HH + c];
    }
    __syncthreads();
    int jg = tid & 63, rg = tid >> 6;
    int ja = jg * 4, jb = 256 + jg * 4;
    float4 acc[4][2];
    #pragma unroll
    for (int r = 0; r < 4; ++r) { acc[r][0] = make_float4(0,0,0,0); acc[r][1] = make_float4(0,0,0,0); }
    #pragma unroll 2
    for (int ko = 0; ko < HH / 4; ++ko) {
        float4 lv[4];
        #pragma unroll
        for (int r = 0; r < 4; ++r) lv[r] = ((const float4*)S[rg * 4 + r])[ko];
        #pragma unroll
        for (int kk = 0; kk < 4; ++kk) {
            int c = ko * 4 + kk;
            float4 b0 = *(const float4*)(po + c * 512 + ja);
            float4 b1 = *(const float4*)(po + c * 512 + jb);
            #pragma unroll
            for (int r = 0; r < 4; ++r) {
                float s = ((const float*)&lv[r])[kk];
                fma4(acc[r][0], b0, s); fma4(acc[r][1], b1, s);
            }
        }
    }
    #pragma unroll
    for (int r = 0; r < 4; ++r) {
        int h = h0 + rg * 4 + r;
        *(float4*)(PWall + h * 2048 + q * 512 + ja) = acc[r][0];
        *(float4*)(PWall + h * 2048 + q * 512 + jb) = acc[r][1];
    }
}

// P2o = p2w@po (8,512); bvec = (p1b+p2b)@po + pob
__global__ __launch_bounds__(512) void k_small(const float* __restrict__ p2w,
    const float* __restrict__ po, const float* __restrict__ p1b,
    const float* __restrict__ p2b, const float* __restrict__ pob,
    float* __restrict__ P2o, float* __restrict__ bvec) {
    int j = threadIdx.x;
    float acc[9];
    #pragma unroll
    for (int r = 0; r < 9; ++r) acc[r] = 0.f;
    for (int c = 0; c < HH; ++c) {
        float pv = po[c * 512 + j];
        #pragma unroll
        for (int r = 0; r < 8; ++r) acc[r] += p2w[r * HH + c] * pv;
        acc[8] += (p1b[c] + p2b[c]) * pv;
    }
    #pragma unroll
    for (int r = 0; r < 8; ++r) P2o[r * 512 + j] = acc[r];
    bvec[j] = acc[8] + pob[j];
}

// A2[(b*512 + q*128 + t), j] = sum_c x[b,t,c] * PWall[c][q*512+j]   (f32, R2-proven)
__global__ __launch_bounds__(256) void k_A2(const float* __restrict__ x,
                                            const float* __restrict__ PWall,
                                            float* __restrict__ A2) {
    __shared__ float S[16][HH];
    int blk = blockIdx.x;        // bt_tile*4 + q
    int q = blk & 3;
    int bt0 = (blk >> 2) * 16;
    int tid = threadIdx.x;
    for (int e = tid; e < 16 * HH; e += 256) {
        int r = e >> 8, c = e & 255;
        S[r][c] = x[(bt0 + r) * HH + c];
    }
    __syncthreads();
    int jg = tid & 63, rg = tid >> 6;
    int ja = jg * 4, jb = 256 + jg * 4;
    float4 acc[4][2];
    #pragma unroll
    for (int r = 0; r < 4; ++r) { acc[r][0] = make_float4(0,0,0,0); acc[r][1] = make_float4(0,0,0,0); }
    #pragma unroll 2
    for (int ko = 0; ko < HH / 4; ++ko) {
        float4 lv[4];
        #pragma unroll
        for (int r = 0; r < 4; ++r) lv[r] = ((const float4*)S[rg * 4 + r])[ko];
        #pragma unroll
        for (int kk = 0; kk < 4; ++kk) {
            int c = ko * 4 + kk;
            float4 b0 = *(const float4*)(PWall + c * 2048 + q * 512 + ja);
            float4 b1 = *(const float4*)(PWall + c * 2048 + q * 512 + jb);
            #pragma unroll
            for (int r = 0; r < 4; ++r) {
                float s = ((const float*)&lv[r])[kk];
                fma4(acc[r][0], b0, s); fma4(acc[r][1], b1, s);
            }
        }
    }
    #pragma unroll
    for (int r = 0; r < 4; ++r) {
        int bt = bt0 + rg * 4 + r;
        int b = bt >> 7, t = bt & 127;
        float* dst = A2 + (size_t)((b * 4 + q) * TT + t) * 512;
        *(float4*)(dst + ja) = acc[r][0];
        *(float4*)(dst + jb) = acc[r][1];
    }
}

// === THE ONLY NEW KERNEL vs the passing R2 build ===
// o = W @ A2 (MFMA bf16, conversion done here) + wc8@P2o + bvec; masked rows -> pob
// block: 256 thr (4 waves), tile 128m x 128n, BK=32
__global__ __launch_bounds__(256) void k_main(
    const float* __restrict__ w_out, const float* __restrict__ A2,
    const float* __restrict__ wc8, const float* __restrict__ P2o,
    const float* __restrict__ bvec, const float* __restrict__ pob,
    const int* __restrict__ ml_i, float* __restrict__ o_out) {
    __shared__ __align__(16) unsigned short Asm[128 * 40];
    __shared__ __align__(16) unsigned short Bsm[128 * 40];
    int blk = blockIdx.x;
    int nt = blk & 3, mt = (blk >> 2) & 7, b = blk >> 5;
    int m0 = mt * 128, n0 = nt * 128;
    int tid = threadIdx.x;
    int lane = tid & 63, wv = tid >> 6;
    int wm = wv & 1, wn = wv >> 1;

    floatx4 acc[16];
    #pragma unroll
    for (int i = 0; i < 16; ++i) acc[i] = (floatx4){0.f, 0.f, 0.f, 0.f};

    int srow = tid >> 1, shalf = tid & 1;
    int arow_base = wm * 64 + (lane & 15);
    int brow_base = wn * 64 + (lane & 15);
    int acol = (lane >> 4) * 8;

    for (int kc = 0; kc < 512; kc += 32) {
        int q = kc >> 7, tk = kc & 127;
        // A-tile: 128 m-rows x 32 k from w_out (f32 -> bf16)
        {
            int m = m0 + srow;
            union { unsigned short us[16]; uint4 q4[2]; } pk;
            if (m < MM) {
                const float* src = w_out + ((size_t)(b * 4 + q) * MM + m) * TT + tk + shalf * 16;
                #pragma unroll
                for (int g = 0; g < 4; ++g) {
                    float4 v = ((const float4*)src)[g];
                    pk.us[g * 4 + 0] = f2bf(v.x); pk.us[g * 4 + 1] = f2bf(v.y);
                    pk.us[g * 4 + 2] = f2bf(v.z); pk.us[g * 4 + 3] = f2bf(v.w);
                }
            } else {
                pk.q4[0] = make_uint4(0, 0, 0, 0);
                pk.q4[1] = make_uint4(0, 0, 0, 0);
            }
            *(uint4*)(&Asm[srow * 40 + shalf * 16]) = pk.q4[0];
            *(uint4*)(&Asm[srow * 40 + shalf * 16 + 8]) = pk.q4[1];
        }
        // B-tile: A2 f32 rows [k][n], coalesced read, transpose-on-write to Bsm[n][k] bf16
        {
            #pragma unroll
            for (int it = 0; it < 4; ++it) {
                int idx = it * 256 + tid;
                int kl = idx >> 5, jq = idx & 31;
                const float* row = A2 + ((size_t)(b * 512) + kc + kl) * 512 + n0 + jq * 4;
                float4 v = *(const float4*)row;
                Bsm[(jq * 4 + 0) * 40 + kl] = f2bf(v.x);
                Bsm[(jq * 4 + 1) * 40 + kl] = f2bf(v.y);
                Bsm[(jq * 4 + 2) * 40 + kl] = f2bf(v.z);
                Bsm[(jq * 4 + 3) * 40 + kl] = f2bf(v.w);
            }
        }
        __syncthreads();
        short8 af[4], bfr[4];
        #pragma unroll
        for (int i = 0; i < 4; ++i)
            af[i] = *(const short8*)(&Asm[(arow_base + i * 16) * 40 + acol]);
        #pragma unroll
        for (int j = 0; j < 4; ++j)
            bfr[j] = *(const short8*)(&Bsm[(brow_base + j * 16) * 40 + acol]);
        #pragma unroll
        for (int i = 0; i < 4; ++i)
            #pragma unroll
            for (int j = 0; j < 4; ++j)
                acc[i * 4 + j] = __builtin_amdgcn_mfma_f32_16x16x32_bf16(
                    af[i], bfr[j], acc[i * 4 + j], 0, 0, 0);
        __syncthreads();
    }

    // epilogue: stage wc8/P2o/bvec/pob slices in LDS (reuse Asm/Bsm)
    float* wc8s = (float*)Asm;           // [128][8]
    float* P2os = (float*)Bsm;           // [8][128]
    float* bvs  = (float*)Bsm + 1024;    // [128]
    float* pobs = (float*)Bsm + 1152;    // [128]
    for (int e = tid; e < 1024; e += 256) {
        int mm_ = e >> 3, r = e & 7;
        int m = m0 + mm_;
        wc8s[e] = (m < MM) ? wc8[((size_t)b * MM + m) * 8 + r] : 0.f;
    }
    for (int e = tid; e < 1024; e += 256) {
        int r = e >> 7, j = e & 127;
        P2os[e] = P2o[r * 512 + n0 + j];
    }
    if (tid < 128) {
        bvs[tid] = bvec[n0 + tid];
        pobs[tid] = pob[n0 + tid];
    }
    __syncthreads();
    int ml = ml_i[b];
    #pragma unroll
    for (int i = 0; i < 4; ++i) {
        #pragma unroll
        for (int j = 0; j < 4; ++j) {
            int nloc = wn * 64 + j * 16 + (lane & 15);
            #pragma unroll
            for (int reg = 0; reg < 4; ++reg) {
                int mloc = wm * 64 + i * 16 + (lane >> 4) * 4 + reg;
                int m = m0 + mloc;
                if (m >= MM) continue;
                float v;
                if (m < ml) {
                    v = acc[i * 4 + j][reg] + bvs[nloc];
                    #pragma unroll
                    for (int r8 = 0; r8 < 8; ++r8)
                        v += wc8s[mloc * 8 + r8] * P2os[r8 * 128 + nloc];
                } else {
                    v = pobs[nloc];
                }
                o_out[((size_t)b * MM + m) * 512 + n0 + nloc] = v;
            }
        }
    }
}

extern "C" void kernel_launch(void* const* d_in, const int* in_sizes, int n_in,
                              void* d_out, int out_size, void* d_ws, size_t ws_size,
                              hipStream_t stream) {
    (void)in_sizes; (void)n_in; (void)out_size; (void)ws_size;
    const float* x      = (const float*)d_in[0];
    const float* dur    = (const float*)d_in[2];
    const int*   xlen   = (const int*)d_in[3];
    const float* proj_w = (const float*)d_in[4];
    const float* proj_b = (const float*)d_in[5];
    const float* conv_w = (const float*)d_in[6];
    const float* conv_b = (const float*)d_in[7];
    const float* conv_g = (const float*)d_in[8];
    const float* conv_be= (const float*)d_in[9];
    const float* q_w1   = (const float*)d_in[10];
    const float* q_b1   = (const float*)d_in[11];
    const float* q_g    = (const float*)d_in[12];
    const float* q_be   = (const float*)d_in[13];
    const float* q_w2   = (const float*)d_in[14];
    const float* q_b2   = (const float*)d_in[15];
    const float* p_w1   = (const float*)d_in[16];
    const float* p_b1   = (const float*)d_in[17];
    const float* p_g    = (const float*)d_in[18];
    const float* p_be   = (const float*)d_in[19];
    const float* p_w2   = (const float*)d_in[20];
    const float* p_b2   = (const float*)d_in[21];
    const float* p1w    = (const float*)d_in[22];
    const float* p1b    = (const float*)d_in[23];
    const float* p2w    = (const float*)d_in[24];
    const float* p2b    = (const float*)d_in[25];
    const float* pow_   = (const float*)d_in[26];
    const float* pob    = (const float*)d_in[27];

    float* ws    = (float*)d_ws;
    float* e_cum = ws + 0;
    float* hcpre = ws + 4096;
    float* baseq = ws + 36864;
    float* basep = ws + 53248;
    float* h     = ws + 61440;
    float* PWall = ws + 1110016;
    float* A2    = ws + 1634304;
    float* wc8   = ws + 10022912;
    float* P2o   = ws + 10278912;
    float* bvec  = ws + 10283008;
    int*   ml_i  = (int*)(ws + 10283520);

    float* o_out  = (float*)d_out;                  // (B,M,512)
    float* mm_out = o_out + 16384000;               // (B,M,T)
    float* ml_out = o_out + 20480000;               // (B,)
    float* w_out  = o_out + 20480032;               // (B,Q,M,T)

    k_prep<<<dim3(BB), dim3(64), 0, stream>>>(dur, e_cum, ml_i, ml_out);
    k_h<<<dim3(BB * 8), dim3(256), 0, stream>>>(x, proj_w, proj_b, h);
    k_conv<<<dim3(BB * 8), dim3(128), 0, stream>>>(h, conv_w, xlen, hcpre);
    k_bases<<<dim3(BB), dim3(128), 0, stream>>>(hcpre, conv_b, conv_g, conv_be,
                                                q_w1, q_b1, p_w1, p_b1,
                                                e_cum, dur, xlen, baseq, basep);
    k_pw<<<dim3(64), dim3(256), 0, stream>>>(p1w, pow_, PWall);
    k_small<<<dim3(1), dim3(512), 0, stream>>>(p2w, pow_, p1b, p2b, pob, P2o, bvec);
    k_A2<<<dim3(BB * TT / 16 * 4), dim3(256), 0, stream>>>(x, PWall, A2);
    k_wsoft<<<dim3(BB * MM), dim3(128), 0, stream>>>(baseq, basep,
                                                     q_w1, q_g, q_be, q_w2, q_b2,
                                                     p_w1, p_g, p_be, p_w2, p_b2,
                                                     xlen, ml_i, w_out, mm_out, wc8);
    k_main<<<dim3(BB * 32), dim3(256), 0, stream>>>(w_out, A2, wc8, P2o, bvec,
                                                    pob, ml_i, o_out);
}

// Round 5
// 561.708 us; speedup vs baseline: 1.3425x; 1.0496x over previous
//
#include <hip/hip_runtime.h>
#include <math.h>

#define BB 32
#define TT 128
#define HH 256
#define MM 1000

typedef __attribute__((ext_vector_type(8))) short short8;
typedef __attribute__((ext_vector_type(4))) float floatx4;

__device__ inline void fma4(float4& a, const float4 b, float s) {
    a.x += b.x * s; a.y += b.y * s; a.z += b.z * s; a.w += b.w * s;
}

__device__ inline unsigned short f2bf(float f) {
    union { float f; unsigned int u; } c; c.f = f;
    unsigned int u = c.u;
    return (unsigned short)((u + 0x7FFFu + ((u >> 16) & 1u)) >> 16);
}

// ---------------- ws layout (floats) ----------------
// e_cum 0 (4096) | hcpre 4096 (32768) | baseq 36864 (16384) | basep 53248 (8192)
// h 61440 (1048576) | PWall 1110016 (524288)
// A2T (ushort) @float 1634304 (8388608 ushorts = 4194304 floats)  [b][n=j][k=q*128+t]
// wc8 5828608 (256000) | P2o 6084608 (4096) | bvec 6088704 (512) | ml_i 6089216

__global__ void k_prep(const float* __restrict__ dur, float* __restrict__ e_cum,
                       int* __restrict__ ml_i, float* __restrict__ ml_out) {
    int b = blockIdx.x;
    if (threadIdx.x == 0) {
        float run = 0.f;
        const float* d = dur + b * TT;
        float* e = e_cum + b * TT;
        for (int t = 0; t < TT; ++t) { run += d[t]; e[t] = run; }
        int ml = (int)rintf(run);
        if (ml > MM) ml = MM;
        if (ml < 0) ml = 0;
        ml_i[b] = ml;
        ml_out[b] = (float)ml;
    }
}

// h = x @ proj_w + proj_b  (R2-proven)
__global__ __launch_bounds__(256) void k_h(const float* __restrict__ x,
                                           const float* __restrict__ pw,
                                           const float* __restrict__ pb,
                                           float* __restrict__ h) {
    __shared__ float xs[16][HH];
    int blk = blockIdx.x;            // b*8 + tt
    int b = blk >> 3, tt = blk & 7;
    int t0 = tt * 16;
    int tid = threadIdx.x;
    for (int e = tid; e < 16 * HH; e += 256) {
        int r = e >> 8, i = e & 255;
        xs[r][i] = x[(b * TT + t0 + r) * HH + i];
    }
    __syncthreads();
    int jg = tid & 63, rg = tid >> 6;
    int j4 = jg * 4;
    float4 bias = *(const float4*)(pb + j4);
    float4 acc[4];
    #pragma unroll
    for (int ri = 0; ri < 4; ++ri) acc[ri] = bias;
    #pragma unroll 4
    for (int i = 0; i < HH; ++i) {
        float4 wv = *(const float4*)(pw + i * HH + j4);
        #pragma unroll
        for (int ri = 0; ri < 4; ++ri) fma4(acc[ri], wv, xs[rg * 4 + ri][i]);
    }
    #pragma unroll
    for (int ri = 0; ri < 4; ++ri)
        *(float4*)(h + (b * TT + t0 + rg * 4 + ri) * HH + j4) = acc[ri];
}

// conv 'SAME' K=3: LDS-staged coalesced; block = (b, 16-t tile), 128 thr = 8 o x 16 t
__global__ __launch_bounds__(128) void k_conv(const float* __restrict__ h,
                                              const float* __restrict__ cw,
                                              const int* __restrict__ xlen,
                                              float* __restrict__ hcpre) {
    __shared__ float hs[18][257];
    __shared__ float cws[8][769];
    int blk = blockIdx.x;            // b*8 + tt
    int b = blk >> 3, tt = blk & 7;
    int t0 = tt * 16;
    int tid = threadIdx.x;
    int L = xlen[b];
    for (int e = tid; e < 18 * 256; e += 128) {
        int r = e >> 8, i = e & 255;
        int t = t0 - 1 + r;
        float v = 0.f;
        if (t >= 0 && t < TT && t < L) v = h[((size_t)b * TT + t) * HH + i];
        hs[r][i] = v;
    }
    for (int e = tid; e < 6144; e += 128) {
        int o = e / 768, rem = e - o * 768;
        cws[o][rem] = cw[e];
    }
    __syncthreads();
    int o = tid >> 4, tl = tid & 15;
    float acc = 0.f;
    #pragma unroll
    for (int k = 0; k < 3; ++k) {
        const float* wr = &cws[o][k];
        const float* hr = hs[tl + k];
        #pragma unroll 8
        for (int i = 0; i < 256; ++i) acc += hr[i] * wr[i * 3];
    }
    hcpre[((size_t)b * TT + t0 + tl) * 8 + o] = acc;
}

__global__ __launch_bounds__(128) void k_bases(
    const float* __restrict__ hcpre, const float* __restrict__ cb,
    const float* __restrict__ cg, const float* __restrict__ cbeta,
    const float* __restrict__ qw1, const float* __restrict__ qb1,
    const float* __restrict__ pw1, const float* __restrict__ pb1,
    const float* __restrict__ e_cum, const float* __restrict__ dur,
    const int* __restrict__ xlen,
    float* __restrict__ baseq, float* __restrict__ basep) {
    int b = blockIdx.x;
    int t = threadIdx.x;
    int L = xlen[b];
    float v[8];
    float mu = 0.f;
    #pragma unroll
    for (int o = 0; o < 8; ++o) { v[o] = hcpre[(b * TT + t) * 8 + o] + cb[o]; mu += v[o]; }
    mu *= 0.125f;
    float var = 0.f;
    #pragma unroll
    for (int o = 0; o < 8; ++o) { float d = v[o] - mu; var += d * d; }
    var *= 0.125f;
    float rs = 1.0f / sqrtf(var + 1e-5f);
    float valid = (t < L) ? 1.f : 0.f;
    #pragma unroll
    for (int o = 0; o < 8; ++o) {
        float a = (v[o] - mu) * rs * cg[o] + cbeta[o];
        v[o] = a / (1.f + expf(-a)) * valid;
    }
    float e = e_cum[b * TT + t];
    float s_ = e - dur[b * TT + t];
    #pragma unroll
    for (int j = 0; j < 4; ++j) {
        float acc = qb1[j];
        #pragma unroll
        for (int o = 0; o < 8; ++o) acc += v[o] * qw1[o * 4 + j];
        acc += e * qw1[9 * 4 + j] - s_ * qw1[8 * 4 + j];
        baseq[(b * TT + t) * 4 + j] = acc;
    }
    #pragma unroll
    for (int j = 0; j < 2; ++j) {
        float acc = pb1[j];
        #pragma unroll
        for (int o = 0; o < 8; ++o) acc += v[o] * pw1[o * 2 + j];
        acc += e * pw1[9 * 2 + j] - s_ * pw1[8 * 2 + j];
        basep[(b * TT + t) * 2 + j] = acc;
    }
}

// wave-per-m: block 256 = 4 waves = 4 m's, no barriers, 64-lane shuffle reductions.
// lane owns t1=lane, t2=lane+64.
__global__ __launch_bounds__(256) void k_wsoft(
    const float* __restrict__ baseq, const float* __restrict__ basep,
    const float* __restrict__ qw1, const float* __restrict__ qg,
    const float* __restrict__ qbeta, const float* __restrict__ qw2,
    const float* __restrict__ qb2,
    const float* __restrict__ pw1, const float* __restrict__ pg,
    const float* __restrict__ pbeta, const float* __restrict__ pw2,
    const float* __restrict__ pb2,
    const int* __restrict__ xlen, const int* __restrict__ ml_i,
    float* __restrict__ w_out, float* __restrict__ mm_out,
    float* __restrict__ wc8) {
    int blk = blockIdx.x;            // b*250 + mg
    int b = blk / 250;
    int mg = blk - b * 250;
    int wv = threadIdx.x >> 6, lane = threadIdx.x & 63;
    int m = mg * 4 + wv;
    int ml = ml_i[b];
    int t1 = lane, t2 = lane + 64;
    bool pad = (m >= ml);
    size_t mmbase = ((size_t)b * MM + m) * TT;
    mm_out[mmbase + t1] = pad ? 1.f : 0.f;
    mm_out[mmbase + t2] = pad ? 1.f : 0.f;
    if (pad) {
        #pragma unroll
        for (int q = 0; q < 4; ++q) {
            size_t wb = ((size_t)(b * 4 + q) * MM + m) * TT;
            w_out[wb + t1] = 0.f;
            w_out[wb + t2] = 0.f;
        }
        if (lane == 0) {
            #pragma unroll
            for (int r = 0; r < 8; ++r) wc8[((size_t)b * MM + m) * 8 + r] = 0.f;
        }
        return;
    }
    int L = xlen[b];
    float mp1 = (float)(m + 1);
    float dq[4];
    #pragma unroll
    for (int j = 0; j < 4; ++j) dq[j] = mp1 * (qw1[8 * 4 + j] - qw1[9 * 4 + j]);

    float sc1[4], sc2[4];
    float c1v[2], c2v[2];
    #pragma unroll
    for (int half = 0; half < 2; ++half) {
        int t = half ? t2 : t1;
        float* sc = half ? sc2 : sc1;
        float* cv = half ? c2v : c1v;
        if (t < L) {
            float4 bq = *(const float4*)(baseq + ((size_t)b * TT + t) * 4);
            float z[4] = {bq.x + dq[0], bq.y + dq[1], bq.z + dq[2], bq.w + dq[3]};
            float mu = 0.25f * (z[0] + z[1] + z[2] + z[3]);
            float var = 0.f;
            #pragma unroll
            for (int j = 0; j < 4; ++j) { float d = z[j] - mu; var += d * d; }
            var *= 0.25f;
            float rs = 1.f / sqrtf(var + 1e-5f);
            float a[4];
            #pragma unroll
            for (int j = 0; j < 4; ++j) {
                float av = (z[j] - mu) * rs * qg[j] + qbeta[j];
                a[j] = av / (1.f + expf(-av));
            }
            #pragma unroll
            for (int q = 0; q < 4; ++q) {
                float s = qb2[q];
                #pragma unroll
                for (int j = 0; j < 4; ++j) s += a[j] * qw2[j * 4 + q];
                sc[q] = s;
            }
            float z0 = basep[((size_t)b * TT + t) * 2 + 0] + mp1 * (pw1[16] - pw1[18]);
            float z1 = basep[((size_t)b * TT + t) * 2 + 1] + mp1 * (pw1[17] - pw1[19]);
            float pmu = 0.5f * (z0 + z1);
            float d0 = z0 - pmu, d1 = z1 - pmu;
            float pvar = 0.5f * (d0 * d0 + d1 * d1);
            float prs = 1.f / sqrtf(pvar + 1e-5f);
            float a0 = d0 * prs * pg[0] + pbeta[0];
            float a1 = d1 * prs * pg[1] + pbeta[1];
            a0 = a0 / (1.f + expf(-a0));
            a1 = a1 / (1.f + expf(-a1));
            cv[0] = pb2[0] + a0 * pw2[0] + a1 * pw2[2];
            cv[1] = pb2[1] + a0 * pw2[1] + a1 * pw2[3];
        } else {
            sc[0] = sc[1] = sc[2] = sc[3] = -__builtin_inff();
            cv[0] = cv[1] = 0.f;
        }
    }
    float w1[4], w2[4];
    #pragma unroll
    for (int q = 0; q < 4; ++q) {
        float mx = fmaxf(sc1[q], sc2[q]);
        #pragma unroll
        for (int off = 32; off > 0; off >>= 1) mx = fmaxf(mx, __shfl_xor(mx, off, 64));
        float e1 = expf(sc1[q] - mx);
        float e2 = expf(sc2[q] - mx);
        float s = e1 + e2;
        #pragma unroll
        for (int off = 32; off > 0; off >>= 1) s += __shfl_xor(s, off, 64);
        w1[q] = e1 / s;
        w2[q] = e2 / s;
        size_t wb = ((size_t)(b * 4 + q) * MM + m) * TT;
        w_out[wb + t1] = w1[q];
        w_out[wb + t2] = w2[q];
    }
    float red[8];
    #pragma unroll
    for (int r8 = 0; r8 < 8; ++r8) {
        int q = r8 >> 1, p = r8 & 1;
        float v = w1[q] * c1v[p] + w2[q] * c2v[p];
        #pragma unroll
        for (int off = 32; off > 0; off >>= 1) v += __shfl_xor(v, off, 64);
        red[r8] = v;
    }
    if (lane == 0) {
        #pragma unroll
        for (int r8 = 0; r8 < 8; ++r8) wc8[((size_t)b * MM + m) * 8 + r8] = red[r8];
    }
}

// PWall[h][q*512+j] = sum_c p1w[q*256+h, c] * po[c, j]
__global__ __launch_bounds__(256) void k_pw(const float* __restrict__ p1w,
                                            const float* __restrict__ po,
                                            float* __restrict__ PWall) {
    __shared__ float S[16][HH];
    int blk = blockIdx.x;        // q*16 + ht
    int q = blk >> 4, ht = blk & 15;
    int h0 = ht * 16;
    int tid = threadIdx.x;
    for (int e = tid; e < 16 * HH; e += 256) {
        int r = e >> 8, c = e & 255;
        S[r][c] = p1w[(q * HH + h0 + r) * HH + c];
    }
    __syncthreads();
    int jg = tid & 63, rg = tid >> 6;
    int ja = jg * 4, jb = 256 + jg * 4;
    float4 acc[4][2];
    #pragma unroll
    for (int r = 0; r < 4; ++r) { acc[r][0] = make_float4(0,0,0,0); acc[r][1] = make_float4(0,0,0,0); }
    #pragma unroll 2
    for (int ko = 0; ko < HH / 4; ++ko) {
        float4 lv[4];
        #pragma unroll
        for (int r = 0; r < 4; ++r) lv[r] = ((const float4*)S[rg * 4 + r])[ko];
        #pragma unroll
        for (int kk = 0; kk < 4; ++kk) {
            int c = ko * 4 + kk;
            float4 b0 = *(const float4*)(po + c * 512 + ja);
            float4 b1 = *(const float4*)(po + c * 512 + jb);
            #pragma unroll
            for (int r = 0; r < 4; ++r) {
                float s = ((const float*)&lv[r])[kk];
                fma4(acc[r][0], b0, s); fma4(acc[r][1], b1, s);
            }
        }
    }
    #pragma unroll
    for (int r = 0; r < 4; ++r) {
        int h = h0 + rg * 4 + r;
        *(float4*)(PWall + h * 2048 + q * 512 + ja) = acc[r][0];
        *(float4*)(PWall + h * 2048 + q * 512 + jb) = acc[r][1];
    }
}

// P2o = p2w@po (8,512); bvec = (p1b+p2b)@po + pob
__global__ __launch_bounds__(512) void k_small(const float* __restrict__ p2w,
    const float* __restrict__ po, const float* __restrict__ p1b,
    const float* __restrict__ p2b, const float* __restrict__ pob,
    float* __restrict__ P2o, float* __restrict__ bvec) {
    int j = threadIdx.x;
    float acc[9];
    #pragma unroll
    for (int r = 0; r < 9; ++r) acc[r] = 0.f;
    for (int c = 0; c < HH; ++c) {
        float pv = po[c * 512 + j];
        #pragma unroll
        for (int r = 0; r < 8; ++r) acc[r] += p2w[r * HH + c] * pv;
        acc[8] += (p1b[c] + p2b[c]) * pv;
    }
    #pragma unroll
    for (int r = 0; r < 8; ++r) P2o[r * 512 + j] = acc[r];
    bvec[j] = acc[8] + pob[j];
}

// A2T[b][n=j][k=q*128+t] = bf16( sum_c x[b,t,c] * PWall[c][q*512+j] )
// compute part R2-proven; output path: LDS transpose [tl][j] then 32B-chunk writes
__global__ __launch_bounds__(256) void k_A2(const float* __restrict__ x,
                                            const float* __restrict__ PWall,
                                            unsigned short* __restrict__ A2T) {
    __shared__ float S[16][HH];
    unsigned short* Tls = (unsigned short*)&S[0][0];   // alias: [16][512] ushorts = 16 KB
    int blk = blockIdx.x;        // bt_tile*4 + q
    int q = blk & 3;
    int bt0 = (blk >> 2) * 16;
    int b = bt0 >> 7, t0 = bt0 & 127;   // 16 | 128 so no b-crossing
    int tid = threadIdx.x;
    for (int e = tid; e < 16 * HH; e += 256) {
        int r = e >> 8, c = e & 255;
        S[r][c] = x[(bt0 + r) * HH + c];
    }
    __syncthreads();
    int jg = tid & 63, rg = tid >> 6;
    int ja = jg * 4, jb = 256 + jg * 4;
    float4 acc[4][2];
    #pragma unroll
    for (int r = 0; r < 4; ++r) { acc[r][0] = make_float4(0,0,0,0); acc[r][1] = make_float4(0,0,0,0); }
    #pragma unroll 2
    for (int ko = 0; ko < HH / 4; ++ko) {
        float4 lv[4];
        #pragma unroll
        for (int r = 0; r < 4; ++r) lv[r] = ((const float4*)S[rg * 4 + r])[ko];
        #pragma unroll
        for (int kk = 0; kk < 4; ++kk) {
            int c = ko * 4 + kk;
            float4 b0 = *(const float4*)(PWall + c * 2048 + q * 512 + ja);
            float4 b1 = *(const float4*)(PWall + c * 2048 + q * 512 + jb);
            #pragma unroll
            for (int r = 0; r < 4; ++r) {
                float s = ((const float*)&lv[r])[kk];
                fma4(acc[r][0], b0, s); fma4(acc[r][1], b1, s);
            }
        }
    }
    __syncthreads();   // all S reads done; safe to overwrite with Tls
    #pragma unroll
    for (int r = 0; r < 4; ++r) {
        int tl = rg * 4 + r;
        Tls[tl * 512 + ja + 0] = f2bf(acc[r][0].x);
        Tls[tl * 512 + ja + 1] = f2bf(acc[r][0].y);
        Tls[tl * 512 + ja + 2] = f2bf(acc[r][0].z);
        Tls[tl * 512 + ja + 3] = f2bf(acc[r][0].w);
        Tls[tl * 512 + jb + 0] = f2bf(acc[r][1].x);
        Tls[tl * 512 + jb + 1] = f2bf(acc[r][1].y);
        Tls[tl * 512 + jb + 2] = f2bf(acc[r][1].z);
        Tls[tl * 512 + jb + 3] = f2bf(acc[r][1].w);
    }
    __syncthreads();
    for (int jj = tid; jj < 512; jj += 256) {
        union { unsigned short us[16]; uint4 v[2]; } pk;
        #pragma unroll
        for (int tl = 0; tl < 16; ++tl) pk.us[tl] = Tls[tl * 512 + jj];
        unsigned short* dst = A2T + ((size_t)b * 512 + jj) * 512 + q * 128 + t0;
        *(uint4*)(dst) = pk.v[0];
        *(uint4*)(dst + 8) = pk.v[1];
    }
}

// o = W @ A2 (MFMA bf16) + wc8@P2o + bvec; masked rows -> pob
// block: 256 thr (4 waves), tile 128m x 128n, BK=32.  B-side: pure bf16 copy.
__global__ __launch_bounds__(256) void k_main(
    const float* __restrict__ w_out, const unsigned short* __restrict__ A2T,
    const float* __restrict__ wc8, const float* __restrict__ P2o,
    const float* __restrict__ bvec, const float* __restrict__ pob,
    const int* __restrict__ ml_i, float* __restrict__ o_out) {
    __shared__ __align__(16) unsigned short Asm[128 * 40];
    __shared__ __align__(16) unsigned short Bsm[128 * 40];
    int blk = blockIdx.x;
    int nt = blk & 3, mt = (blk >> 2) & 7, b = blk >> 5;
    int m0 = mt * 128, n0 = nt * 128;
    int tid = threadIdx.x;
    int lane = tid & 63, wv = tid >> 6;
    int wm = wv & 1, wn = wv >> 1;

    floatx4 acc[16];
    #pragma unroll
    for (int i = 0; i < 16; ++i) acc[i] = (floatx4){0.f, 0.f, 0.f, 0.f};

    int srow = tid >> 1, shalf = tid & 1;
    int arow_base = wm * 64 + (lane & 15);
    int brow_base = wn * 64 + (lane & 15);
    int acol = (lane >> 4) * 8;

    for (int kc = 0; kc < 512; kc += 32) {
        int q = kc >> 7, tk = kc & 127;
        // A-tile: 128 m-rows x 32 k from w_out (f32 -> bf16)
        {
            int m = m0 + srow;
            union { unsigned short us[16]; uint4 q4[2]; } pk;
            if (m < MM) {
                const float* src = w_out + ((size_t)(b * 4 + q) * MM + m) * TT + tk + shalf * 16;
                #pragma unroll
                for (int g = 0; g < 4; ++g) {
                    float4 v = ((const float4*)src)[g];
                    pk.us[g * 4 + 0] = f2bf(v.x); pk.us[g * 4 + 1] = f2bf(v.y);
                    pk.us[g * 4 + 2] = f2bf(v.z); pk.us[g * 4 + 3] = f2bf(v.w);
                }
            } else {
                pk.q4[0] = make_uint4(0, 0, 0, 0);
                pk.q4[1] = make_uint4(0, 0, 0, 0);
            }
            *(uint4*)(&Asm[srow * 40 + shalf * 16]) = pk.q4[0];
            *(uint4*)(&Asm[srow * 40 + shalf * 16 + 8]) = pk.q4[1];
        }
        // B-tile: straight bf16 copy from A2T[b][n0+srow][kc + shalf*16 ..]
        {
            const unsigned short* srcB = A2T + ((size_t)b * 512 + n0 + srow) * 512 + kc + shalf * 16;
            uint4 v0 = *(const uint4*)srcB;
            uint4 v1 = *(const uint4*)(srcB + 8);
            *(uint4*)(&Bsm[srow * 40 + shalf * 16]) = v0;
            *(uint4*)(&Bsm[srow * 40 + shalf * 16 + 8]) = v1;
        }
        __syncthreads();
        short8 af[4], bfr[4];
        #pragma unroll
        for (int i = 0; i < 4; ++i)
            af[i] = *(const short8*)(&Asm[(arow_base + i * 16) * 40 + acol]);
        #pragma unroll
        for (int j = 0; j < 4; ++j)
            bfr[j] = *(const short8*)(&Bsm[(brow_base + j * 16) * 40 + acol]);
        #pragma unroll
        for (int i = 0; i < 4; ++i)
            #pragma unroll
            for (int j = 0; j < 4; ++j)
                acc[i * 4 + j] = __builtin_amdgcn_mfma_f32_16x16x32_bf16(
                    af[i], bfr[j], acc[i * 4 + j], 0, 0, 0);
        __syncthreads();
    }

    // epilogue: stage wc8/P2o/bvec/pob slices in LDS (reuse Asm/Bsm)
    float* wc8s = (float*)Asm;           // [128][8]
    float* P2os = (float*)Bsm;           // [8][128]
    float* bvs  = (float*)Bsm + 1024;    // [128]
    float* pobs = (float*)Bsm + 1152;    // [128]
    for (int e = tid; e < 1024; e += 256) {
        int mm_ = e >> 3, r = e & 7;
        int m = m0 + mm_;
        wc8s[e] = (m < MM) ? wc8[((size_t)b * MM + m) * 8 + r] : 0.f;
    }
    for (int e = tid; e < 1024; e += 256) {
        int r = e >> 7, j = e & 127;
        P2os[e] = P2o[r * 512 + n0 + j];
    }
    if (tid < 128) {
        bvs[tid] = bvec[n0 + tid];
        pobs[tid] = pob[n0 + tid];
    }
    __syncthreads();
    int ml = ml_i[b];
    #pragma unroll
    for (int i = 0; i < 4; ++i) {
        #pragma unroll
        for (int j = 0; j < 4; ++j) {
            int nloc = wn * 64 + j * 16 + (lane & 15);
            #pragma unroll
            for (int reg = 0; reg < 4; ++reg) {
                int mloc = wm * 64 + i * 16 + (lane >> 4) * 4 + reg;
                int m = m0 + mloc;
                if (m >= MM) continue;
                float v;
                if (m < ml) {
                    v = acc[i * 4 + j][reg] + bvs[nloc];
                    #pragma unroll
                    for (int r8 = 0; r8 < 8; ++r8)
                        v += wc8s[mloc * 8 + r8] * P2os[r8 * 128 + nloc];
                } else {
                    v = pobs[nloc];
                }
                o_out[((size_t)b * MM + m) * 512 + n0 + nloc] = v;
            }
        }
    }
}

extern "C" void kernel_launch(void* const* d_in, const int* in_sizes, int n_in,
                              void* d_out, int out_size, void* d_ws, size_t ws_size,
                              hipStream_t stream) {
    (void)in_sizes; (void)n_in; (void)out_size; (void)ws_size;
    const float* x      = (const float*)d_in[0];
    const float* dur    = (const float*)d_in[2];
    const int*   xlen   = (const int*)d_in[3];
    const float* proj_w = (const float*)d_in[4];
    const float* proj_b = (const float*)d_in[5];
    const float* conv_w = (const float*)d_in[6];
    const float* conv_b = (const float*)d_in[7];
    const float* conv_g = (const float*)d_in[8];
    const float* conv_be= (const float*)d_in[9];
    const float* q_w1   = (const float*)d_in[10];
    const float* q_b1   = (const float*)d_in[11];
    const float* q_g    = (const float*)d_in[12];
    const float* q_be   = (const float*)d_in[13];
    const float* q_w2   = (const float*)d_in[14];
    const float* q_b2   = (const float*)d_in[15];
    const float* p_w1   = (const float*)d_in[16];
    const float* p_b1   = (const float*)d_in[17];
    const float* p_g    = (const float*)d_in[18];
    const float* p_be   = (const float*)d_in[19];
    const float* p_w2   = (const float*)d_in[20];
    const float* p_b2   = (const float*)d_in[21];
    const float* p1w    = (const float*)d_in[22];
    const float* p1b    = (const float*)d_in[23];
    const float* p2w    = (const float*)d_in[24];
    const float* p2b    = (const float*)d_in[25];
    const float* pow_   = (const float*)d_in[26];
    const float* pob    = (const float*)d_in[27];

    float* ws    = (float*)d_ws;
    float* e_cum = ws + 0;
    float* hcpre = ws + 4096;
    float* baseq = ws + 36864;
    float* basep = ws + 53248;
    float* h     = ws + 61440;
    float* PWall = ws + 1110016;
    unsigned short* A2T = (unsigned short*)(ws + 1634304);
    float* wc8   = ws + 5828608;
    float* P2o   = ws + 6084608;
    float* bvec  = ws + 6088704;
    int*   ml_i  = (int*)(ws + 6089216);

    float* o_out  = (float*)d_out;                  // (B,M,512)
    float* mm_out = o_out + 16384000;               // (B,M,T)
    float* ml_out = o_out + 20480000;               // (B,)
    float* w_out  = o_out + 20480032;               // (B,Q,M,T)

    k_prep<<<dim3(BB), dim3(64), 0, stream>>>(dur, e_cum, ml_i, ml_out);
    k_h<<<dim3(BB * 8), dim3(256), 0, stream>>>(x, proj_w, proj_b, h);
    k_conv<<<dim3(BB * 8), dim3(128), 0, stream>>>(h, conv_w, xlen, hcpre);
    k_bases<<<dim3(BB), dim3(128), 0, stream>>>(hcpre, conv_b, conv_g, conv_be,
                                                q_w1, q_b1, p_w1, p_b1,
                                                e_cum, dur, xlen, baseq, basep);
    k_pw<<<dim3(64), dim3(256), 0, stream>>>(p1w, pow_, PWall);
    k_small<<<dim3(1), dim3(512), 0, stream>>>(p2w, pow_, p1b, p2b, pob, P2o, bvec);
    k_A2<<<dim3(BB * TT / 16 * 4), dim3(256), 0, stream>>>(x, PWall, A2T);
    k_wsoft<<<dim3(BB * 250), dim3(256), 0, stream>>>(baseq, basep,
                                                      q_w1, q_g, q_be, q_w2, q_b2,
                                                      p_w1, p_g, p_be, p_w2, p_b2,
                                                      xlen, ml_i, w_out, mm_out, wc8);
    k_main<<<dim3(BB * 32), dim3(256), 0, stream>>>(w_out, A2T, wc8, P2o, bvec,
                                                    pob, ml_i, o_out);
}

// Round 6
// 482.608 us; speedup vs baseline: 1.5626x; 1.1639x over previous
//
#include <hip/hip_runtime.h>
#include <math.h>

#define BB 32
#define TT 128
#define HH 256
#define MM 1000

typedef __attribute__((ext_vector_type(8))) short short8;
typedef __attribute__((ext_vector_type(4))) float floatx4;

__device__ inline void fma4(float4& a, const float4 b, float s) {
    a.x += b.x * s; a.y += b.y * s; a.z += b.z * s; a.w += b.w * s;
}

__device__ inline unsigned short f2bf(float f) {
    union { float f; unsigned int u; } c; c.f = f;
    unsigned int u = c.u;
    return (unsigned short)((u + 0x7FFFu + ((u >> 16) & 1u)) >> 16);
}

// ---------------- ws layout (floats) ----------------
// e_cum 0 (4096) | hcpre 4096 (32768) | baseq 36864 (16384) | basep 53248 (8192)
// h 61440 (1048576) | PWall 1110016 (524288)
// A2T (ushort) @float 1634304 (8388608 ushorts = 4194304 floats)  [b][n=j][k=q*128+t]
// wc8 5828608 (256000) | P2o 6084608 (4096) | bvec 6088704 (512) | ml_i 6089216
// PWpart 6090752 (2097152)  [ks=4][h=256][2048]

__global__ void k_prep(const float* __restrict__ dur, float* __restrict__ e_cum,
                       int* __restrict__ ml_i, float* __restrict__ ml_out) {
    int b = blockIdx.x;
    if (threadIdx.x == 0) {
        float run = 0.f;
        const float* d = dur + b * TT;
        float* e = e_cum + b * TT;
        for (int t = 0; t < TT; ++t) { run += d[t]; e[t] = run; }
        int ml = (int)rintf(run);
        if (ml > MM) ml = MM;
        if (ml < 0) ml = 0;
        ml_i[b] = ml;
        ml_out[b] = (float)ml;
    }
}

// h = x @ proj_w + proj_b  (R2-proven)
__global__ __launch_bounds__(256) void k_h(const float* __restrict__ x,
                                           const float* __restrict__ pw,
                                           const float* __restrict__ pb,
                                           float* __restrict__ h) {
    __shared__ float xs[16][HH];
    int blk = blockIdx.x;            // b*8 + tt
    int b = blk >> 3, tt = blk & 7;
    int t0 = tt * 16;
    int tid = threadIdx.x;
    for (int e = tid; e < 16 * HH; e += 256) {
        int r = e >> 8, i = e & 255;
        xs[r][i] = x[(b * TT + t0 + r) * HH + i];
    }
    __syncthreads();
    int jg = tid & 63, rg = tid >> 6;
    int j4 = jg * 4;
    float4 bias = *(const float4*)(pb + j4);
    float4 acc[4];
    #pragma unroll
    for (int ri = 0; ri < 4; ++ri) acc[ri] = bias;
    #pragma unroll 4
    for (int i = 0; i < HH; ++i) {
        float4 wv = *(const float4*)(pw + i * HH + j4);
        #pragma unroll
        for (int ri = 0; ri < 4; ++ri) fma4(acc[ri], wv, xs[rg * 4 + ri][i]);
    }
    #pragma unroll
    for (int ri = 0; ri < 4; ++ri)
        *(float4*)(h + (b * TT + t0 + rg * 4 + ri) * HH + j4) = acc[ri];
}

// conv 'SAME' K=3: LDS-staged coalesced; block = (b, 16-t tile), 128 thr = 8 o x 16 t
__global__ __launch_bounds__(128) void k_conv(const float* __restrict__ h,
                                              const float* __restrict__ cw,
                                              const int* __restrict__ xlen,
                                              float* __restrict__ hcpre) {
    __shared__ float hs[18][257];
    __shared__ float cws[8][769];
    int blk = blockIdx.x;            // b*8 + tt
    int b = blk >> 3, tt = blk & 7;
    int t0 = tt * 16;
    int tid = threadIdx.x;
    int L = xlen[b];
    for (int e = tid; e < 18 * 256; e += 128) {
        int r = e >> 8, i = e & 255;
        int t = t0 - 1 + r;
        float v = 0.f;
        if (t >= 0 && t < TT && t < L) v = h[((size_t)b * TT + t) * HH + i];
        hs[r][i] = v;
    }
    for (int e = tid; e < 6144; e += 128) {
        int o = e / 768, rem = e - o * 768;
        cws[o][rem] = cw[e];
    }
    __syncthreads();
    int o = tid >> 4, tl = tid & 15;
    float acc = 0.f;
    #pragma unroll
    for (int k = 0; k < 3; ++k) {
        const float* wr = &cws[o][k];
        const float* hr = hs[tl + k];
        #pragma unroll 8
        for (int i = 0; i < 256; ++i) acc += hr[i] * wr[i * 3];
    }
    hcpre[((size_t)b * TT + t0 + tl) * 8 + o] = acc;
}

__global__ __launch_bounds__(128) void k_bases(
    const float* __restrict__ hcpre, const float* __restrict__ cb,
    const float* __restrict__ cg, const float* __restrict__ cbeta,
    const float* __restrict__ qw1, const float* __restrict__ qb1,
    const float* __restrict__ pw1, const float* __restrict__ pb1,
    const float* __restrict__ e_cum, const float* __restrict__ dur,
    const int* __restrict__ xlen,
    float* __restrict__ baseq, float* __restrict__ basep) {
    int b = blockIdx.x;
    int t = threadIdx.x;
    int L = xlen[b];
    float v[8];
    float mu = 0.f;
    #pragma unroll
    for (int o = 0; o < 8; ++o) { v[o] = hcpre[(b * TT + t) * 8 + o] + cb[o]; mu += v[o]; }
    mu *= 0.125f;
    float var = 0.f;
    #pragma unroll
    for (int o = 0; o < 8; ++o) { float d = v[o] - mu; var += d * d; }
    var *= 0.125f;
    float rs = 1.0f / sqrtf(var + 1e-5f);
    float valid = (t < L) ? 1.f : 0.f;
    #pragma unroll
    for (int o = 0; o < 8; ++o) {
        float a = (v[o] - mu) * rs * cg[o] + cbeta[o];
        v[o] = a / (1.f + expf(-a)) * valid;
    }
    float e = e_cum[b * TT + t];
    float s_ = e - dur[b * TT + t];
    #pragma unroll
    for (int j = 0; j < 4; ++j) {
        float acc = qb1[j];
        #pragma unroll
        for (int o = 0; o < 8; ++o) acc += v[o] * qw1[o * 4 + j];
        acc += e * qw1[9 * 4 + j] - s_ * qw1[8 * 4 + j];
        baseq[(b * TT + t) * 4 + j] = acc;
    }
    #pragma unroll
    for (int j = 0; j < 2; ++j) {
        float acc = pb1[j];
        #pragma unroll
        for (int o = 0; o < 8; ++o) acc += v[o] * pw1[o * 2 + j];
        acc += e * pw1[9 * 2 + j] - s_ * pw1[8 * 2 + j];
        basep[(b * TT + t) * 2 + j] = acc;
    }
}

// wave-per-m: block 256 = 4 waves = 4 m's, no barriers (R5-proven)
__global__ __launch_bounds__(256) void k_wsoft(
    const float* __restrict__ baseq, const float* __restrict__ basep,
    const float* __restrict__ qw1, const float* __restrict__ qg,
    const float* __restrict__ qbeta, const float* __restrict__ qw2,
    const float* __restrict__ qb2,
    const float* __restrict__ pw1, const float* __restrict__ pg,
    const float* __restrict__ pbeta, const float* __restrict__ pw2,
    const float* __restrict__ pb2,
    const int* __restrict__ xlen, const int* __restrict__ ml_i,
    float* __restrict__ w_out, float* __restrict__ mm_out,
    float* __restrict__ wc8) {
    int blk = blockIdx.x;            // b*250 + mg
    int b = blk / 250;
    int mg = blk - b * 250;
    int wv = threadIdx.x >> 6, lane = threadIdx.x & 63;
    int m = mg * 4 + wv;
    int ml = ml_i[b];
    int t1 = lane, t2 = lane + 64;
    bool pad = (m >= ml);
    size_t mmbase = ((size_t)b * MM + m) * TT;
    mm_out[mmbase + t1] = pad ? 1.f : 0.f;
    mm_out[mmbase + t2] = pad ? 1.f : 0.f;
    if (pad) {
        #pragma unroll
        for (int q = 0; q < 4; ++q) {
            size_t wb = ((size_t)(b * 4 + q) * MM + m) * TT;
            w_out[wb + t1] = 0.f;
            w_out[wb + t2] = 0.f;
        }
        if (lane == 0) {
            #pragma unroll
            for (int r = 0; r < 8; ++r) wc8[((size_t)b * MM + m) * 8 + r] = 0.f;
        }
        return;
    }
    int L = xlen[b];
    float mp1 = (float)(m + 1);
    float dq[4];
    #pragma unroll
    for (int j = 0; j < 4; ++j) dq[j] = mp1 * (qw1[8 * 4 + j] - qw1[9 * 4 + j]);

    float sc1[4], sc2[4];
    float c1v[2], c2v[2];
    #pragma unroll
    for (int half = 0; half < 2; ++half) {
        int t = half ? t2 : t1;
        float* sc = half ? sc2 : sc1;
        float* cv = half ? c2v : c1v;
        if (t < L) {
            float4 bq = *(const float4*)(baseq + ((size_t)b * TT + t) * 4);
            float z[4] = {bq.x + dq[0], bq.y + dq[1], bq.z + dq[2], bq.w + dq[3]};
            float mu = 0.25f * (z[0] + z[1] + z[2] + z[3]);
            float var = 0.f;
            #pragma unroll
            for (int j = 0; j < 4; ++j) { float d = z[j] - mu; var += d * d; }
            var *= 0.25f;
            float rs = 1.f / sqrtf(var + 1e-5f);
            float a[4];
            #pragma unroll
            for (int j = 0; j < 4; ++j) {
                float av = (z[j] - mu) * rs * qg[j] + qbeta[j];
                a[j] = av / (1.f + expf(-av));
            }
            #pragma unroll
            for (int q = 0; q < 4; ++q) {
                float s = qb2[q];
                #pragma unroll
                for (int j = 0; j < 4; ++j) s += a[j] * qw2[j * 4 + q];
                sc[q] = s;
            }
            float z0 = basep[((size_t)b * TT + t) * 2 + 0] + mp1 * (pw1[16] - pw1[18]);
            float z1 = basep[((size_t)b * TT + t) * 2 + 1] + mp1 * (pw1[17] - pw1[19]);
            float pmu = 0.5f * (z0 + z1);
            float d0 = z0 - pmu, d1 = z1 - pmu;
            float pvar = 0.5f * (d0 * d0 + d1 * d1);
            float prs = 1.f / sqrtf(pvar + 1e-5f);
            float a0 = d0 * prs * pg[0] + pbeta[0];
            float a1 = d1 * prs * pg[1] + pbeta[1];
            a0 = a0 / (1.f + expf(-a0));
            a1 = a1 / (1.f + expf(-a1));
            cv[0] = pb2[0] + a0 * pw2[0] + a1 * pw2[2];
            cv[1] = pb2[1] + a0 * pw2[1] + a1 * pw2[3];
        } else {
            sc[0] = sc[1] = sc[2] = sc[3] = -__builtin_inff();
            cv[0] = cv[1] = 0.f;
        }
    }
    float w1[4], w2[4];
    #pragma unroll
    for (int q = 0; q < 4; ++q) {
        float mx = fmaxf(sc1[q], sc2[q]);
        #pragma unroll
        for (int off = 32; off > 0; off >>= 1) mx = fmaxf(mx, __shfl_xor(mx, off, 64));
        float e1 = expf(sc1[q] - mx);
        float e2 = expf(sc2[q] - mx);
        float s = e1 + e2;
        #pragma unroll
        for (int off = 32; off > 0; off >>= 1) s += __shfl_xor(s, off, 64);
        w1[q] = e1 / s;
        w2[q] = e2 / s;
        size_t wb = ((size_t)(b * 4 + q) * MM + m) * TT;
        w_out[wb + t1] = w1[q];
        w_out[wb + t2] = w2[q];
    }
    float red[8];
    #pragma unroll
    for (int r8 = 0; r8 < 8; ++r8) {
        int q = r8 >> 1, p = r8 & 1;
        float v = w1[q] * c1v[p] + w2[q] * c2v[p];
        #pragma unroll
        for (int off = 32; off > 0; off >>= 1) v += __shfl_xor(v, off, 64);
        red[r8] = v;
    }
    if (lane == 0) {
        #pragma unroll
        for (int r8 = 0; r8 < 8; ++r8) wc8[((size_t)b * MM + m) * 8 + r8] = red[r8];
    }
}

// === k-split replacement for k_pw (the 104 us latency-bound kernel) ===
// PWpart[ks][h][q*512+j] = sum_{c in 64-slice} p1w[q*256+h, c] * po[c, j]
// grid: ht(16) x colT(8: q*2+jhalf) x ks(4) = 512 blocks, 256 thr
__global__ __launch_bounds__(256) void k_pw_part(const float* __restrict__ p1w,
                                                 const float* __restrict__ po,
                                                 float* __restrict__ PWpart) {
    __shared__ float S[16][64];
    int blk = blockIdx.x;
    int ks = blk & 3, colT = (blk >> 2) & 7, ht = blk >> 5;
    int q = colT >> 1, j0 = (colT & 1) * 256;
    int h0 = ht * 16, k0 = ks * 64;
    int tid = threadIdx.x;
    for (int e = tid; e < 1024; e += 256) {
        int r = e >> 6, c = e & 63;
        S[r][c] = p1w[(q * 256 + h0 + r) * 256 + k0 + c];
    }
    __syncthreads();
    int jg = tid & 63, rg = tid >> 6;
    int jcol = j0 + jg * 4;
    float4 acc[4];
    #pragma unroll
    for (int r = 0; r < 4; ++r) acc[r] = make_float4(0, 0, 0, 0);
    // register double-buffer on the B load
    float4 nb = *(const float4*)(po + (size_t)k0 * 512 + jcol);
    for (int c = 0; c < 64; ++c) {
        float4 cur = nb;
        if (c < 63) nb = *(const float4*)(po + (size_t)(k0 + c + 1) * 512 + jcol);
        #pragma unroll
        for (int r = 0; r < 4; ++r) fma4(acc[r], cur, S[rg * 4 + r][c]);
    }
    #pragma unroll
    for (int r = 0; r < 4; ++r) {
        int hh = h0 + rg * 4 + r;
        *(float4*)(PWpart + (size_t)ks * 524288 + hh * 2048 + q * 512 + jcol) = acc[r];
    }
}

// PWall = sum_ks PWpart[ks]
__global__ __launch_bounds__(256) void k_pwred(const float* __restrict__ PWpart,
                                               float* __restrict__ PWall) {
    int idx = blockIdx.x * 256 + threadIdx.x;
    size_t e = (size_t)idx * 4;
    float4 v = *(const float4*)(PWpart + e);
    float4 v1 = *(const float4*)(PWpart + 524288 + e);
    float4 v2 = *(const float4*)(PWpart + 2 * 524288 + e);
    float4 v3 = *(const float4*)(PWpart + 3 * 524288 + e);
    v.x += v1.x + v2.x + v3.x;
    v.y += v1.y + v2.y + v3.y;
    v.z += v1.z + v2.z + v3.z;
    v.w += v1.w + v2.w + v3.w;
    *(float4*)(PWall + e) = v;
}

// P2o = p2w@po (8,512); bvec = (p1b+p2b)@po + pob
__global__ __launch_bounds__(512) void k_small(const float* __restrict__ p2w,
    const float* __restrict__ po, const float* __restrict__ p1b,
    const float* __restrict__ p2b, const float* __restrict__ pob,
    float* __restrict__ P2o, float* __restrict__ bvec) {
    int j = threadIdx.x;
    float acc[9];
    #pragma unroll
    for (int r = 0; r < 9; ++r) acc[r] = 0.f;
    for (int c = 0; c < HH; ++c) {
        float pv = po[c * 512 + j];
        #pragma unroll
        for (int r = 0; r < 8; ++r) acc[r] += p2w[r * HH + c] * pv;
        acc[8] += (p1b[c] + p2b[c]) * pv;
    }
    #pragma unroll
    for (int r = 0; r < 8; ++r) P2o[r * 512 + j] = acc[r];
    bvec[j] = acc[8] + pob[j];
}

// A2T[b][n=j][k=q*128+t] = bf16( sum_c x[b,t,c] * PWall[c][q*512+j] )  (R5-proven)
__global__ __launch_bounds__(256) void k_A2(const float* __restrict__ x,
                                            const float* __restrict__ PWall,
                                            unsigned short* __restrict__ A2T) {
    __shared__ float S[16][HH];
    unsigned short* Tls = (unsigned short*)&S[0][0];   // alias: [16][512] ushorts = 16 KB
    int blk = blockIdx.x;        // bt_tile*4 + q
    int q = blk & 3;
    int bt0 = (blk >> 2) * 16;
    int b = bt0 >> 7, t0 = bt0 & 127;   // 16 | 128 so no b-crossing
    int tid = threadIdx.x;
    for (int e = tid; e < 16 * HH; e += 256) {
        int r = e >> 8, c = e & 255;
        S[r][c] = x[(bt0 + r) * HH + c];
    }
    __syncthreads();
    int jg = tid & 63, rg = tid >> 6;
    int ja = jg * 4, jb = 256 + jg * 4;
    float4 acc[4][2];
    #pragma unroll
    for (int r = 0; r < 4; ++r) { acc[r][0] = make_float4(0,0,0,0); acc[r][1] = make_float4(0,0,0,0); }
    #pragma unroll 2
    for (int ko = 0; ko < HH / 4; ++ko) {
        float4 lv[4];
        #pragma unroll
        for (int r = 0; r < 4; ++r) lv[r] = ((const float4*)S[rg * 4 + r])[ko];
        #pragma unroll
        for (int kk = 0; kk < 4; ++kk) {
            int c = ko * 4 + kk;
            float4 b0 = *(const float4*)(PWall + c * 2048 + q * 512 + ja);
            float4 b1 = *(const float4*)(PWall + c * 2048 + q * 512 + jb);
            #pragma unroll
            for (int r = 0; r < 4; ++r) {
                float s = ((const float*)&lv[r])[kk];
                fma4(acc[r][0], b0, s); fma4(acc[r][1], b1, s);
            }
        }
    }
    __syncthreads();   // all S reads done; safe to overwrite with Tls
    #pragma unroll
    for (int r = 0; r < 4; ++r) {
        int tl = rg * 4 + r;
        Tls[tl * 512 + ja + 0] = f2bf(acc[r][0].x);
        Tls[tl * 512 + ja + 1] = f2bf(acc[r][0].y);
        Tls[tl * 512 + ja + 2] = f2bf(acc[r][0].z);
        Tls[tl * 512 + ja + 3] = f2bf(acc[r][0].w);
        Tls[tl * 512 + jb + 0] = f2bf(acc[r][1].x);
        Tls[tl * 512 + jb + 1] = f2bf(acc[r][1].y);
        Tls[tl * 512 + jb + 2] = f2bf(acc[r][1].z);
        Tls[tl * 512 + jb + 3] = f2bf(acc[r][1].w);
    }
    __syncthreads();
    for (int jj = tid; jj < 512; jj += 256) {
        union { unsigned short us[16]; uint4 v[2]; } pk;
        #pragma unroll
        for (int tl = 0; tl < 16; ++tl) pk.us[tl] = Tls[tl * 512 + jj];
        unsigned short* dst = A2T + ((size_t)b * 512 + jj) * 512 + q * 128 + t0;
        *(uint4*)(dst) = pk.v[0];
        *(uint4*)(dst + 8) = pk.v[1];
    }
}

// o = W @ A2 (MFMA bf16) + wc8@P2o + bvec; masked rows -> pob   (R5-proven)
__global__ __launch_bounds__(256) void k_main(
    const float* __restrict__ w_out, const unsigned short* __restrict__ A2T,
    const float* __restrict__ wc8, const float* __restrict__ P2o,
    const float* __restrict__ bvec, const float* __restrict__ pob,
    const int* __restrict__ ml_i, float* __restrict__ o_out) {
    __shared__ __align__(16) unsigned short Asm[128 * 40];
    __shared__ __align__(16) unsigned short Bsm[128 * 40];
    int blk = blockIdx.x;
    int nt = blk & 3, mt = (blk >> 2) & 7, b = blk >> 5;
    int m0 = mt * 128, n0 = nt * 128;
    int tid = threadIdx.x;
    int lane = tid & 63, wv = tid >> 6;
    int wm = wv & 1, wn = wv >> 1;

    floatx4 acc[16];
    #pragma unroll
    for (int i = 0; i < 16; ++i) acc[i] = (floatx4){0.f, 0.f, 0.f, 0.f};

    int srow = tid >> 1, shalf = tid & 1;
    int arow_base = wm * 64 + (lane & 15);
    int brow_base = wn * 64 + (lane & 15);
    int acol = (lane >> 4) * 8;

    for (int kc = 0; kc < 512; kc += 32) {
        int q = kc >> 7, tk = kc & 127;
        // A-tile: 128 m-rows x 32 k from w_out (f32 -> bf16)
        {
            int m = m0 + srow;
            union { unsigned short us[16]; uint4 q4[2]; } pk;
            if (m < MM) {
                const float* src = w_out + ((size_t)(b * 4 + q) * MM + m) * TT + tk + shalf * 16;
                #pragma unroll
                for (int g = 0; g < 4; ++g) {
                    float4 v = ((const float4*)src)[g];
                    pk.us[g * 4 + 0] = f2bf(v.x); pk.us[g * 4 + 1] = f2bf(v.y);
                    pk.us[g * 4 + 2] = f2bf(v.z); pk.us[g * 4 + 3] = f2bf(v.w);
                }
            } else {
                pk.q4[0] = make_uint4(0, 0, 0, 0);
                pk.q4[1] = make_uint4(0, 0, 0, 0);
            }
            *(uint4*)(&Asm[srow * 40 + shalf * 16]) = pk.q4[0];
            *(uint4*)(&Asm[srow * 40 + shalf * 16 + 8]) = pk.q4[1];
        }
        // B-tile: straight bf16 copy from A2T[b][n0+srow][kc + shalf*16 ..]
        {
            const unsigned short* srcB = A2T + ((size_t)b * 512 + n0 + srow) * 512 + kc + shalf * 16;
            uint4 v0 = *(const uint4*)srcB;
            uint4 v1 = *(const uint4*)(srcB + 8);
            *(uint4*)(&Bsm[srow * 40 + shalf * 16]) = v0;
            *(uint4*)(&Bsm[srow * 40 + shalf * 16 + 8]) = v1;
        }
        __syncthreads();
        short8 af[4], bfr[4];
        #pragma unroll
        for (int i = 0; i < 4; ++i)
            af[i] = *(const short8*)(&Asm[(arow_base + i * 16) * 40 + acol]);
        #pragma unroll
        for (int j = 0; j < 4; ++j)
            bfr[j] = *(const short8*)(&Bsm[(brow_base + j * 16) * 40 + acol]);
        #pragma unroll
        for (int i = 0; i < 4; ++i)
            #pragma unroll
            for (int j = 0; j < 4; ++j)
                acc[i * 4 + j] = __builtin_amdgcn_mfma_f32_16x16x32_bf16(
                    af[i], bfr[j], acc[i * 4 + j], 0, 0, 0);
        __syncthreads();
    }

    // epilogue: stage wc8/P2o/bvec/pob slices in LDS (reuse Asm/Bsm)
    float* wc8s = (float*)Asm;           // [128][8]
    float* P2os = (float*)Bsm;           // [8][128]
    float* bvs  = (float*)Bsm + 1024;    // [128]
    float* pobs = (float*)Bsm + 1152;    // [128]
    for (int e = tid; e < 1024; e += 256) {
        int mm_ = e >> 3, r = e & 7;
        int m = m0 + mm_;
        wc8s[e] = (m < MM) ? wc8[((size_t)b * MM + m) * 8 + r] : 0.f;
    }
    for (int e = tid; e < 1024; e += 256) {
        int r = e >> 7, j = e & 127;
        P2os[e] = P2o[r * 512 + n0 + j];
    }
    if (tid < 128) {
        bvs[tid] = bvec[n0 + tid];
        pobs[tid] = pob[n0 + tid];
    }
    __syncthreads();
    int ml = ml_i[b];
    #pragma unroll
    for (int i = 0; i < 4; ++i) {
        #pragma unroll
        for (int j = 0; j < 4; ++j) {
            int nloc = wn * 64 + j * 16 + (lane & 15);
            #pragma unroll
            for (int reg = 0; reg < 4; ++reg) {
                int mloc = wm * 64 + i * 16 + (lane >> 4) * 4 + reg;
                int m = m0 + mloc;
                if (m >= MM) continue;
                float v;
                if (m < ml) {
                    v = acc[i * 4 + j][reg] + bvs[nloc];
                    #pragma unroll
                    for (int r8 = 0; r8 < 8; ++r8)
                        v += wc8s[mloc * 8 + r8] * P2os[r8 * 128 + nloc];
                } else {
                    v = pobs[nloc];
                }
                o_out[((size_t)b * MM + m) * 512 + n0 + nloc] = v;
            }
        }
    }
}

extern "C" void kernel_launch(void* const* d_in, const int* in_sizes, int n_in,
                              void* d_out, int out_size, void* d_ws, size_t ws_size,
                              hipStream_t stream) {
    (void)in_sizes; (void)n_in; (void)out_size; (void)ws_size;
    const float* x      = (const float*)d_in[0];
    const float* dur    = (const float*)d_in[2];
    const int*   xlen   = (const int*)d_in[3];
    const float* proj_w = (const float*)d_in[4];
    const float* proj_b = (const float*)d_in[5];
    const float* conv_w = (const float*)d_in[6];
    const float* conv_b = (const float*)d_in[7];
    const float* conv_g = (const float*)d_in[8];
    const float* conv_be= (const float*)d_in[9];
    const float* q_w1   = (const float*)d_in[10];
    const float* q_b1   = (const float*)d_in[11];
    const float* q_g    = (const float*)d_in[12];
    const float* q_be   = (const float*)d_in[13];
    const float* q_w2   = (const float*)d_in[14];
    const float* q_b2   = (const float*)d_in[15];
    const float* p_w1   = (const float*)d_in[16];
    const float* p_b1   = (const float*)d_in[17];
    const float* p_g    = (const float*)d_in[18];
    const float* p_be   = (const float*)d_in[19];
    const float* p_w2   = (const float*)d_in[20];
    const float* p_b2   = (const float*)d_in[21];
    const float* p1w    = (const float*)d_in[22];
    const float* p1b    = (const float*)d_in[23];
    const float* p2w    = (const float*)d_in[24];
    const float* p2b    = (const float*)d_in[25];
    const float* pow_   = (const float*)d_in[26];
    const float* pob    = (const float*)d_in[27];

    float* ws    = (float*)d_ws;
    float* e_cum = ws + 0;
    float* hcpre = ws + 4096;
    float* baseq = ws + 36864;
    float* basep = ws + 53248;
    float* h     = ws + 61440;
    float* PWall = ws + 1110016;
    unsigned short* A2T = (unsigned short*)(ws + 1634304);
    float* wc8   = ws + 5828608;
    float* P2o   = ws + 6084608;
    float* bvec  = ws + 6088704;
    int*   ml_i  = (int*)(ws + 6089216);
    float* PWpart= ws + 6090752;

    float* o_out  = (float*)d_out;                  // (B,M,512)
    float* mm_out = o_out + 16384000;               // (B,M,T)
    float* ml_out = o_out + 20480000;               // (B,)
    float* w_out  = o_out + 20480032;               // (B,Q,M,T)

    k_prep<<<dim3(BB), dim3(64), 0, stream>>>(dur, e_cum, ml_i, ml_out);
    k_h<<<dim3(BB * 8), dim3(256), 0, stream>>>(x, proj_w, proj_b, h);
    k_conv<<<dim3(BB * 8), dim3(128), 0, stream>>>(h, conv_w, xlen, hcpre);
    k_bases<<<dim3(BB), dim3(128), 0, stream>>>(hcpre, conv_b, conv_g, conv_be,
                                                q_w1, q_b1, p_w1, p_b1,
                                                e_cum, dur, xlen, baseq, basep);
    k_pw_part<<<dim3(512), dim3(256), 0, stream>>>(p1w, pow_, PWpart);
    k_pwred<<<dim3(512), dim3(256), 0, stream>>>(PWpart, PWall);
    k_small<<<dim3(1), dim3(512), 0, stream>>>(p2w, pow_, p1b, p2b, pob, P2o, bvec);
    k_A2<<<dim3(BB * TT / 16 * 4), dim3(256), 0, stream>>>(x, PWall, A2T);
    k_wsoft<<<dim3(BB * 250), dim3(256), 0, stream>>>(baseq, basep,
                                                      q_w1, q_g, q_be, q_w2, q_b2,
                                                      p_w1, p_g, p_be, p_w2, p_b2,
                                                      xlen, ml_i, w_out, mm_out, wc8);
    k_main<<<dim3(BB * 32), dim3(256), 0, stream>>>(w_out, A2T, wc8, P2o, bvec,
                                                    pob, ml_i, o_out);
}